// Round 1
// baseline (26026.886 us; speedup 1.0000x reference)
//
#include <hip/hip_runtime.h>
#include <math.h>

#define BDIM 1024
#define DDIM 512
#define VDIM 128
#define TDIM 201
#define FD   2048            // 4*D
#define LN_EPS 1e-5f
#define LOSCALE 4096.0f
#define INV_LOSCALE (1.0f/4096.0f)

// ws layout in floats (total 5,308,416 floats = 20.25 MiB)
#define OFF_C   0            // B*D      c state
#define OFF_CTX 524288       // B*D      context (constant across steps)
#define OFF_E   1048576      // V*FD     E = embed @ W_ih^T + b_ih + b_hh
#define OFF_CP  1310720      // B*V      ctx @ proj^T
#define OFF_LC  1441792      // B*V      current logits (for argmax)
#define OFF_G   1572864      // B*FD     raw gates (before E add)
#define OFF_AHI 3670016      // 64*16*64*8 f16 = 262144 floats: A hi frags
#define OFF_ALO 3932160      // A lo frags (scaled by 4096)
#define OFF_BHI 4194304      // 136*16*64*8 f16 = 557056 floats: B hi frags
#define OFF_BLO 4751360      // B lo frags (scaled by 4096)

typedef _Float16 v8hf __attribute__((ext_vector_type(8)));
typedef float    v4f  __attribute__((ext_vector_type(4)));

// Per-row-group barrier counters (16 groups, 128 B apart to avoid line sharing).
// Monotonic within one kernel_launch; reset by k_init each run (stream-ordered),
// so hipGraph replays and rocprof dispatch replays cannot deadlock: a stale
// (large) counter makes barriers fall through, never hang.
__device__ unsigned int g_bar[16 * 32];

// Fragment-major layouts (16x16x32 f16 MFMA):
//   A operand: lane l holds A[m = mt*16 + (l&15)][k = kt*32 + (l>>4)*8 + j]
//     Afrag[((mt*16 + kt)*64 + l)*8 + j]
//   B operand: lane l holds W[n = nt*16 + (l&15)][k = kt*32 + (l>>4)*8 + j]
//   C/D: col = lane&15, row = (lane>>4)*4 + reg   (m89/m91 verified)
//
// Precision: x = hi + lo/4096 with |x - hi - lo/4096| <= 2^-24|x|.
// Products: hi*hi -> acc1 ; hi*lo + lo*hi -> acc2 ; result = acc1 + acc2/4096.

__device__ __forceinline__ void split_write(float x, _Float16* hiArr, _Float16* loArr,
                                            int row, int k)
{
    _Float16 hi = (_Float16)x;
    _Float16 lo = (_Float16)((x - (float)hi) * LOSCALE);
    int lane = (row & 15) | (((k >> 3) & 3) << 4);
    size_t idx = ((size_t)((row >> 4) * 16 + (k >> 5)) * 64 + lane) * 8 + (k & 7);
    hiArr[idx] = hi;
    loArr[idx] = lo;
}

// Group barrier across the 34 blocks of one row-group (64 rows).
// Agent-scope release on the add publishes this block's prior global stores
// (per-XCD L2 writeback); relaxed agent-scope polls bypass non-coherent caches;
// the final acquire load invalidates L1/L2 so subsequent plain loads see fresh
// data from other XCDs. Bounded spin: converts a logic bug into fast failure
// instead of a harness timeout (legit waits are ~1e2 polls; cap is 4e6).
__device__ __forceinline__ void group_barrier(unsigned int* bar, unsigned int target)
{
    __syncthreads();
    if (threadIdx.x == 0) {
        __hip_atomic_fetch_add(bar, 1u, __ATOMIC_RELEASE, __HIP_MEMORY_SCOPE_AGENT);
        unsigned int spins = 0;
        while (__hip_atomic_load(bar, __ATOMIC_RELAXED, __HIP_MEMORY_SCOPE_AGENT) < target) {
            __builtin_amdgcn_s_sleep(2);
            if (++spins > (1u << 22)) break;
        }
        (void)__hip_atomic_load(bar, __ATOMIC_ACQUIRE, __HIP_MEMORY_SCOPE_AGENT);
    }
    __syncthreads();
}

// ---------------------------------------------------------------------------
// init: LayerNorm(pooled) -> h0 ; c0 = 0 ; softmax(fm@wf) -> context ;
// write A-fragments of (h0 + ctx). Also resets barrier counters.
// ---------------------------------------------------------------------------
__global__ void k_init(const float* __restrict__ fm, const float* __restrict__ pooled,
                       const float* __restrict__ gamma, const float* __restrict__ beta,
                       const float* __restrict__ attn_w, float* __restrict__ ws)
{
    int b = blockIdx.x;
    int t = threadIdx.x;                 // 256 threads
    __shared__ float red[256];
    __shared__ float s_sc[49];
    __shared__ float s_aw[49];
    __shared__ float s_ctx[DDIM];

    if (b == 0 && t < 16) g_bar[t * 32] = 0u;   // barrier reset (stream-ordered before k_loop)

    const float* prow = pooled + (size_t)b * DDIM;
    float x0 = prow[t], x1 = prow[t + 256];
    red[t] = x0 + x1;
    __syncthreads();
    for (int s = 128; s > 0; s >>= 1) { if (t < s) red[t] += red[t + s]; __syncthreads(); }
    float mu = red[0] * (1.0f / DDIM);
    __syncthreads();
    float d0 = x0 - mu, d1 = x1 - mu;
    red[t] = d0 * d0 + d1 * d1;
    __syncthreads();
    for (int s = 128; s > 0; s >>= 1) { if (t < s) red[t] += red[t + s]; __syncthreads(); }
    float rstd = rsqrtf(red[0] * (1.0f / DDIM) + LN_EPS);

    float h0 = d0 * rstd * gamma[t]       + beta[t];
    float h1 = d1 * rstd * gamma[t + 256] + beta[t + 256];

    float* c = ws + OFF_C + (size_t)b * DDIM;
    c[t] = 0.0f;
    c[t + 256] = 0.0f;

    // scores[k] = sum_d fm[b,d,k] * wf[d]   (fm layout: (B, D, 49))
    if (t < 49) {
        const float* base = fm + (size_t)b * DDIM * 49 + t;
        float acc = 0.0f;
        for (int d = 0; d < DDIM; ++d) acc += base[(size_t)d * 49] * attn_w[d];
        s_sc[t] = acc;
    }
    __syncthreads();
    if (t == 0) {
        float mx = s_sc[0];
        for (int k = 1; k < 49; ++k) mx = fmaxf(mx, s_sc[k]);
        float sum = 0.0f;
        for (int k = 0; k < 49; ++k) { float e = expf(s_sc[k] - mx); s_aw[k] = e; sum += e; }
        float inv = 1.0f / sum;
        for (int k = 0; k < 49; ++k) s_aw[k] *= inv;
    }
    __syncthreads();

    float* ctx = ws + OFF_CTX + (size_t)b * DDIM;
    for (int d = t; d < DDIM; d += 256) {
        const float* base = fm + ((size_t)b * DDIM + d) * 49;
        float acc = 0.0f;
        for (int k = 0; k < 49; ++k) acc += s_aw[k] * base[k];
        ctx[d] = acc;
        s_ctx[d] = acc;
    }
    __syncthreads();

    _Float16* Ahi = (_Float16*)(ws + OFF_AHI);
    _Float16* Alo = (_Float16*)(ws + OFF_ALO);
    split_write(h0 + s_ctx[t],       Ahi, Alo, b, t);
    split_write(h1 + s_ctx[t + 256], Ahi, Alo, b, t + 256);
}

// ---------------------------------------------------------------------------
// E[v, n] = sum_d embed[v,d] * W_ih[n,d] + b_ih[n] + b_hh[n]   (128 x 2048)
// ---------------------------------------------------------------------------
__global__ void k_E(const float* __restrict__ embed, const float* __restrict__ W_ih,
                    const float* __restrict__ b_ih, const float* __restrict__ b_hh,
                    float* __restrict__ ws)
{
    int n = blockIdx.x;
    int t = threadIdx.x;                 // 256 threads
    __shared__ float wrow[DDIM];
    wrow[t]       = W_ih[(size_t)n * DDIM + t];
    wrow[t + 256] = W_ih[(size_t)n * DDIM + t + 256];
    __syncthreads();
    if (t < VDIM) {
        const float* er = embed + (size_t)t * DDIM;
        float acc = 0.0f;
        for (int d = 0; d < DDIM; ++d) acc += er[d] * wrow[d];
        ws[OFF_E + (size_t)t * FD + n] = acc + b_ih[n] + b_hh[n];
    }
}

// ---------------------------------------------------------------------------
// ctxproj[b, v] = sum_d ctx[b,d] * proj_w[v,d]
// ---------------------------------------------------------------------------
__global__ void k_cp(const float* __restrict__ proj_w, float* __restrict__ ws)
{
    int b = blockIdx.x;
    int t = threadIdx.x;                 // 128 threads, one per v
    __shared__ float crow[DDIM];
    const float* ctx = ws + OFF_CTX + (size_t)b * DDIM;
    for (int d = t; d < DDIM; d += 128) crow[d] = ctx[d];
    __syncthreads();
    const float* pr = proj_w + (size_t)t * DDIM;
    float acc = 0.0f;
    for (int d = 0; d < DDIM; ++d) acc += crow[d] * pr[d];
    ws[OFF_CP + (size_t)b * VDIM + t] = acc;
}

// ---------------------------------------------------------------------------
// One-time: convert [W_hh | proj_w] (2176 x 512) to fragment-major f16 hi/lo
// ---------------------------------------------------------------------------
__global__ void k_bsetup(const float* __restrict__ W_hh, const float* __restrict__ proj_w,
                         float* __restrict__ ws)
{
    int n = blockIdx.x;                  // 0..2175
    int t = threadIdx.x;                 // 256
    const float* src = (n < FD) ? (W_hh + (size_t)n * DDIM)
                                : (proj_w + (size_t)(n - FD) * DDIM);
    _Float16* Bhi = (_Float16*)(ws + OFF_BHI);
    _Float16* Blo = (_Float16*)(ws + OFF_BLO);
    for (int k = t; k < DDIM; k += 256)
        split_write(src[k], Bhi, Blo, n, k);
}

// ---------------------------------------------------------------------------
// Persistent time loop. Grid 544 = 16 row-groups x 34 col-tiles, 256 thr.
// Row-group rt = blk & 15 owns rows [rt*64, rt*64+64): gates, logits, argmax,
// pointwise, and A-fragments for those rows only ever touch blocks with the
// same rt  ->  34-block group barriers instead of grid sync / kernel launches.
// rt = blk & 15 also makes group members share blk%8 (same XCD under the
// usual round-robin mapping) -- locality only, correctness is scope-fenced.
//
// __launch_bounds__(256, 3) is REQUIRED: it caps VGPRs so 3 blocks/CU fit
// (capacity 768 >= 544), guaranteeing every block is resident -> no deadlock.
// ---------------------------------------------------------------------------
__global__ __launch_bounds__(256, 3) void k_loop(
        const float* __restrict__ proj_b, float* __restrict__ ws,
        float* __restrict__ out, const int* __restrict__ sos_p)
{
    const int blk = blockIdx.x;          // 0..543
    const int rt  = blk & 15;            // row-group
    const int ct  = blk >> 4;            // 0..33 col tile group
    const int tid = threadIdx.x;
    const int w = tid >> 6, lane = tid & 63;
    const int mt  = rt * 4 + w;          // this wave's mtile (0..63)
    const int ntb = ct * 4;              // first of 4 ntiles (0..135)

    unsigned int* bar = &g_bar[rt * 32];

    const v8hf* Ah = (const v8hf*)(ws + OFF_AHI);
    const v8hf* Al = (const v8hf*)(ws + OFF_ALO);
    const v8hf* Bh = (const v8hf*)(ws + OFF_BHI);
    const v8hf* Bl = (const v8hf*)(ws + OFF_BLO);
    const int aBase = mt * 16;

    __shared__ int s_id;
    unsigned int phase = 0;

    for (int tau = 0; tau <= 201; ++tau) {
        // tau 0: gates only; tau 1..200: gates + logits(tau-1); tau 201: logits(200) only
        const bool doGemm = (tau == 0) ? (ct < 32) : (tau == 201) ? (ct >= 32) : true;
        const int  tout   = (tau >= 1) ? (tau - 1) : -1;

        if (doGemm) {
            v4f acc1[4], acc2[4];
#pragma unroll
            for (int nt = 0; nt < 4; ++nt) {
                acc1[nt] = (v4f){0.f, 0.f, 0.f, 0.f};
                acc2[nt] = (v4f){0.f, 0.f, 0.f, 0.f};
            }

            v8hf ah = Ah[(aBase + 0) * 64 + lane];
            v8hf al = Al[(aBase + 0) * 64 + lane];
            v8hf bh[4], bl[4];
#pragma unroll
            for (int nt = 0; nt < 4; ++nt) {
                bh[nt] = Bh[((ntb + nt) * 16 + 0) * 64 + lane];
                bl[nt] = Bl[((ntb + nt) * 16 + 0) * 64 + lane];
            }

#pragma unroll
            for (int kt = 0; kt < 16; ++kt) {
                v8hf nah, nal, nbh[4], nbl[4];
                if (kt < 15) {
                    int k1 = kt + 1;
                    nah = Ah[(aBase + k1) * 64 + lane];
                    nal = Al[(aBase + k1) * 64 + lane];
#pragma unroll
                    for (int nt = 0; nt < 4; ++nt) {
                        nbh[nt] = Bh[((ntb + nt) * 16 + k1) * 64 + lane];
                        nbl[nt] = Bl[((ntb + nt) * 16 + k1) * 64 + lane];
                    }
                }
#pragma unroll
                for (int nt = 0; nt < 4; ++nt) {
                    acc1[nt] = __builtin_amdgcn_mfma_f32_16x16x32_f16(ah, bh[nt], acc1[nt], 0, 0, 0);
                    acc2[nt] = __builtin_amdgcn_mfma_f32_16x16x32_f16(ah, bl[nt], acc2[nt], 0, 0, 0);
                    acc2[nt] = __builtin_amdgcn_mfma_f32_16x16x32_f16(al, bh[nt], acc2[nt], 0, 0, 0);
                }
                if (kt < 15) {
                    ah = nah; al = nal;
#pragma unroll
                    for (int nt = 0; nt < 4; ++nt) { bh[nt] = nbh[nt]; bl[nt] = nbl[nt]; }
                }
            }

            // Epilogue. C/D: col = lane&15, row = (lane>>4)*4 + reg
            int nloc = lane & 15;
            int mrow = mt * 16 + (lane >> 4) * 4;
            if (ntb < 128) {             // gates tiles
                float* g = ws + OFF_G;
#pragma unroll
                for (int nt = 0; nt < 4; ++nt) {
                    int n = (ntb + nt) * 16 + nloc;
#pragma unroll
                    for (int r = 0; r < 4; ++r)
                        g[(size_t)(mrow + r) * FD + n] = acc1[nt][r] + acc2[nt][r] * INV_LOSCALE;
                }
            } else {                     // logits tiles
#pragma unroll
                for (int nt = 0; nt < 4; ++nt) {
                    int v = (ntb + nt) * 16 + nloc - FD;
#pragma unroll
                    for (int r = 0; r < 4; ++r) {
                        int b = mrow + r;
                        float val = acc1[nt][r] + acc2[nt][r] * INV_LOSCALE;
                        float lg = val - ws[OFF_CP + (size_t)b * VDIM + v] + proj_b[v];
                        if (tout >= 0) {
                            out[((size_t)b * VDIM + v) * TDIM + tout] = lg;
                            ws[OFF_LC + (size_t)b * VDIM + v] = lg;
                        }
                    }
                }
            }
        }

        if (tau == 201) break;

        ++phase;
        group_barrier(bar, phase * 34u);     // gates/logits -> pointwise

        // -------- pointwise phase: blocks ct<32 own rows rt*64 + ct*2 + {0,1}
        if (ct < 32) {
            const int doArgmax = (tau >= 1);
#pragma unroll
            for (int rr = 0; rr < 2; ++rr) {
                const int b = rt * 64 + ct * 2 + rr;
                if (doArgmax) {
                    if (w == 0) {        // wave 0: first-index argmax over 128 logits
                        const float* lc = ws + OFF_LC + (size_t)b * VDIM;
                        float bv = lc[lane];
                        int   bi = lane;
                        float v1 = lc[lane + 64];
                        if (v1 > bv) { bv = v1; bi = lane + 64; }
                        for (int off = 32; off > 0; off >>= 1) {
                            float ov = __shfl_down(bv, off);
                            int   oi = __shfl_down(bi, off);
                            if (ov > bv || (ov == bv && oi < bi)) { bv = ov; bi = oi; }
                        }
                        if (lane == 0) s_id = bi;
                    }
                } else if (tid == 0) {
                    s_id = sos_p[0];
                }
                __syncthreads();
                const int id = s_id;

                const float* g   = ws + OFF_G   + (size_t)b * FD;
                const float* E   = ws + OFF_E   + (size_t)id * FD;
                const float* ctx = ws + OFF_CTX + (size_t)b * DDIM;
                float* c = ws + OFF_C + (size_t)b * DDIM;
                _Float16* Ahi = (_Float16*)(ws + OFF_AHI);
                _Float16* Alo = (_Float16*)(ws + OFF_ALO);

                for (int d = tid; d < DDIM; d += 256) {
                    float gi = g[d]            + E[d];
                    float gf = g[d + DDIM]     + E[d + DDIM];
                    float gg = g[d + 2 * DDIM] + E[d + 2 * DDIM];
                    float go = g[d + 3 * DDIM] + E[d + 3 * DDIM];
                    float cv = c[d];
                    float si = 1.0f / (1.0f + expf(-gi));
                    float sf = 1.0f / (1.0f + expf(-gf));
                    float so = 1.0f / (1.0f + expf(-go));
                    float cn = sf * cv + si * tanhf(gg);
                    c[d] = cn;
                    float hn = so * tanhf(cn);
                    split_write(hn + ctx[d], Ahi, Alo, b, d);
                }
                __syncthreads();         // s_id reuse guard
            }
        }

        ++phase;
        group_barrier(bar, phase * 34u);     // A-fragments -> next GEMM
    }
}

extern "C" void kernel_launch(void* const* d_in, const int* in_sizes, int n_in,
                              void* d_out, int out_size, void* d_ws, size_t ws_size,
                              hipStream_t stream)
{
    const float* fm     = (const float*)d_in[0];
    const float* pooled = (const float*)d_in[1];
    const float* gamma  = (const float*)d_in[2];
    const float* beta   = (const float*)d_in[3];
    const float* W_ih   = (const float*)d_in[4];
    const float* W_hh   = (const float*)d_in[5];
    const float* b_ih   = (const float*)d_in[6];
    const float* b_hh   = (const float*)d_in[7];
    const float* embed  = (const float*)d_in[8];
    const float* attn_w = (const float*)d_in[9];
    // d_in[10] = attn_b : provably unused (softmax shift invariance)
    const float* proj_w = (const float*)d_in[11];
    const float* proj_b = (const float*)d_in[12];
    const int*   sos_p  = (const int*)d_in[13];

    float* ws  = (float*)d_ws;
    float* out = (float*)d_out;

    k_init<<<BDIM, 256, 0, stream>>>(fm, pooled, gamma, beta, attn_w, ws);
    k_E<<<FD, 256, 0, stream>>>(embed, W_ih, b_ih, b_hh, ws);
    k_cp<<<BDIM, 128, 0, stream>>>(proj_w, ws);
    k_bsetup<<<FD + VDIM, 256, 0, stream>>>(W_hh, proj_w, ws);

    // Entire 201-step recurrence in ONE persistent kernel (was 402 launches).
    k_loop<<<dim3(544), 256, 0, stream>>>(proj_b, ws, out, sos_p);
}

// Round 2
// 19614.102 us; speedup vs baseline: 1.3269x; 1.3269x over previous
//
#include <hip/hip_runtime.h>
#include <math.h>

#define BDIM 1024
#define DDIM 512
#define VDIM 128
#define TDIM 201
#define FD   2048            // 4*D
#define LN_EPS 1e-5f
#define LOSCALE 4096.0f
#define INV_LOSCALE (1.0f/4096.0f)

// ws layout in floats (total 5,308,416 floats = 20.25 MiB)
#define OFF_C   0            // B*D      c state (now register-resident; kept for debug)
#define OFF_CTX 524288       // B*D      context (constant across steps)
#define OFF_E   1048576      // V*FD     E = embed @ W_ih^T + b_ih + b_hh
#define OFF_CP  1310720      // B*V      ctx @ proj^T
#define OFF_LC  1441792      // B*V      current logits (for argmax)   [coherent]
#define OFF_G   1572864      // B*FD     raw gates (before E add)      [coherent]
#define OFF_AHI 3670016      // 64*16*64*8 f16: A hi frags             [coherent]
#define OFF_ALO 3932160      // A lo frags (scaled by 4096)            [coherent]
#define OFF_BHI 4194304      // 136*16*64*8 f16: B hi frags            [read-only]
#define OFF_BLO 4751360      // B lo frags                             [read-only]

typedef _Float16 v8hf __attribute__((ext_vector_type(8)));
typedef float    v4f  __attribute__((ext_vector_type(4)));
typedef unsigned long long u64;

#define AGENT __HIP_MEMORY_SCOPE_AGENT
#define RLX   __ATOMIC_RELAXED

// Per-row-group barrier counters (16 groups, 128 B apart).
// Monotonic within one launch; reset by k_init (stream-ordered before k_loop),
// so graph replays / rocprof replays can't deadlock on stale values.
__device__ unsigned int g_bar[16 * 32];

// ---- cache-bypass (agent-coherent) helpers -------------------------------
// Relaxed agent-scope atomics lower to global_load/store with sc0+sc1 set:
// they bypass L1 and the (non-cross-XCD-coherent) L2 and hit the coherent
// point (L3). Crucially: NO acquire/release FENCES -> no buffer_inv -> the
// read-only L2 working set (B frags, E, CP, ctx) stays warm for all steps.
__device__ __forceinline__ float co_load_f(const float* p) {
    return __hip_atomic_load((float*)p, RLX, AGENT);
}
__device__ __forceinline__ void co_store_f(float* p, float v) {
    __hip_atomic_store(p, v, RLX, AGENT);
}
__device__ __forceinline__ u64 co_load_u64(const void* p) {
    return __hip_atomic_load((u64*)p, RLX, AGENT);
}
__device__ __forceinline__ void co_store_u64(void* p, u64 v) {
    __hip_atomic_store((u64*)p, v, RLX, AGENT);
}
__device__ __forceinline__ v8hf co_load_frag(const v8hf* arr, int idx) {
    union { u64 u[2]; v8hf h; } r;
    const u64* p = (const u64*)(arr + idx);
    r.u[0] = co_load_u64(p);
    r.u[1] = co_load_u64(p + 1);
    return r.h;
}
__device__ __forceinline__ void co_store_h4(_Float16* p, _Float16 a, _Float16 b,
                                            _Float16 c, _Float16 d) {
    union { _Float16 h[4]; u64 u; } pk;
    pk.h[0] = a; pk.h[1] = b; pk.h[2] = c; pk.h[3] = d;
    co_store_u64(p, pk.u);
}

// Group barrier across the 34 blocks of one row-group.
// Producer ordering: the __syncthreads() drains each thread's vmcnt before
// s_barrier (compiler-emitted s_waitcnt vmcnt(0)), so every cross-block
// (bypass) store has reached the coherent point before thread 0's add is
// issued. Consumer ordering: data loads sit after the dependent poll branch
// (in-order issue) and behind a compiler memory barrier. NO cache fences.
// Bounded spin: a logic bug fails fast (wrong results) instead of hanging.
__device__ __forceinline__ void group_barrier(unsigned int* bar, unsigned int target)
{
    __syncthreads();
    if (threadIdx.x == 0) {
        __hip_atomic_fetch_add(bar, 1u, RLX, AGENT);
        unsigned int spins = 0;
        while (__hip_atomic_load(bar, RLX, AGENT) < target) {
            __builtin_amdgcn_s_sleep(1);
            if (++spins > (1u << 24)) break;
        }
    }
    __syncthreads();
    asm volatile("" ::: "memory");
    __builtin_amdgcn_sched_barrier(0);
}

// Fragment-major layouts (16x16x32 f16 MFMA):
//   A operand: lane l holds A[m = mt*16 + (l&15)][k = kt*32 + (l>>4)*8 + j]
//     Afrag[((mt*16 + kt)*64 + l)*8 + j]
//   B operand: lane l holds W[n = nt*16 + (l&15)][k = kt*32 + (l>>4)*8 + j]
//   C/D: col = lane&15, row = (lane>>4)*4 + reg   (m89/m91 verified)
//
// Precision: x = hi + lo/4096, products hi*hi->acc1, hi*lo+lo*hi->acc2,
// result = acc1 + acc2/4096 (lo*lo dropped, ~2^-24).

__device__ __forceinline__ void split_write(float x, _Float16* hiArr, _Float16* loArr,
                                            int row, int k)
{
    _Float16 hi = (_Float16)x;
    _Float16 lo = (_Float16)((x - (float)hi) * LOSCALE);
    int lane = (row & 15) | (((k >> 3) & 3) << 4);
    size_t idx = ((size_t)((row >> 4) * 16 + (k >> 5)) * 64 + lane) * 8 + (k & 7);
    hiArr[idx] = hi;
    loArr[idx] = lo;
}

// ---------------------------------------------------------------------------
// init: LayerNorm(pooled) -> h0 ; softmax(fm@wf) -> context ;
// write A-fragments of (h0 + ctx). Also resets barrier counters.
// ---------------------------------------------------------------------------
__global__ void k_init(const float* __restrict__ fm, const float* __restrict__ pooled,
                       const float* __restrict__ gamma, const float* __restrict__ beta,
                       const float* __restrict__ attn_w, float* __restrict__ ws)
{
    int b = blockIdx.x;
    int t = threadIdx.x;                 // 256 threads
    __shared__ float red[256];
    __shared__ float s_sc[49];
    __shared__ float s_aw[49];
    __shared__ float s_ctx[DDIM];

    if (b == 0 && t < 16) g_bar[t * 32] = 0u;   // barrier reset

    const float* prow = pooled + (size_t)b * DDIM;
    float x0 = prow[t], x1 = prow[t + 256];
    red[t] = x0 + x1;
    __syncthreads();
    for (int s = 128; s > 0; s >>= 1) { if (t < s) red[t] += red[t + s]; __syncthreads(); }
    float mu = red[0] * (1.0f / DDIM);
    __syncthreads();
    float d0 = x0 - mu, d1 = x1 - mu;
    red[t] = d0 * d0 + d1 * d1;
    __syncthreads();
    for (int s = 128; s > 0; s >>= 1) { if (t < s) red[t] += red[t + s]; __syncthreads(); }
    float rstd = rsqrtf(red[0] * (1.0f / DDIM) + LN_EPS);

    float h0 = d0 * rstd * gamma[t]       + beta[t];
    float h1 = d1 * rstd * gamma[t + 256] + beta[t + 256];

    float* c = ws + OFF_C + (size_t)b * DDIM;
    c[t] = 0.0f;
    c[t + 256] = 0.0f;

    // scores[k] = sum_d fm[b,d,k] * wf[d]   (fm layout: (B, D, 49))
    if (t < 49) {
        const float* base = fm + (size_t)b * DDIM * 49 + t;
        float acc = 0.0f;
        for (int d = 0; d < DDIM; ++d) acc += base[(size_t)d * 49] * attn_w[d];
        s_sc[t] = acc;
    }
    __syncthreads();
    if (t == 0) {
        float mx = s_sc[0];
        for (int k = 1; k < 49; ++k) mx = fmaxf(mx, s_sc[k]);
        float sum = 0.0f;
        for (int k = 0; k < 49; ++k) { float e = expf(s_sc[k] - mx); s_aw[k] = e; sum += e; }
        float inv = 1.0f / sum;
        for (int k = 0; k < 49; ++k) s_aw[k] *= inv;
    }
    __syncthreads();

    float* ctx = ws + OFF_CTX + (size_t)b * DDIM;
    for (int d = t; d < DDIM; d += 256) {
        const float* base = fm + ((size_t)b * DDIM + d) * 49;
        float acc = 0.0f;
        for (int k = 0; k < 49; ++k) acc += s_aw[k] * base[k];
        ctx[d] = acc;
        s_ctx[d] = acc;
    }
    __syncthreads();

    _Float16* Ahi = (_Float16*)(ws + OFF_AHI);
    _Float16* Alo = (_Float16*)(ws + OFF_ALO);
    split_write(h0 + s_ctx[t],       Ahi, Alo, b, t);
    split_write(h1 + s_ctx[t + 256], Ahi, Alo, b, t + 256);
}

// ---------------------------------------------------------------------------
// E[v, n] = sum_d embed[v,d] * W_ih[n,d] + b_ih[n] + b_hh[n]   (128 x 2048)
// ---------------------------------------------------------------------------
__global__ void k_E(const float* __restrict__ embed, const float* __restrict__ W_ih,
                    const float* __restrict__ b_ih, const float* __restrict__ b_hh,
                    float* __restrict__ ws)
{
    int n = blockIdx.x;
    int t = threadIdx.x;                 // 256 threads
    __shared__ float wrow[DDIM];
    wrow[t]       = W_ih[(size_t)n * DDIM + t];
    wrow[t + 256] = W_ih[(size_t)n * DDIM + t + 256];
    __syncthreads();
    if (t < VDIM) {
        const float* er = embed + (size_t)t * DDIM;
        float acc = 0.0f;
        for (int d = 0; d < DDIM; ++d) acc += er[d] * wrow[d];
        ws[OFF_E + (size_t)t * FD + n] = acc + b_ih[n] + b_hh[n];
    }
}

// ---------------------------------------------------------------------------
// ctxproj[b, v] = sum_d ctx[b,d] * proj_w[v,d]
// ---------------------------------------------------------------------------
__global__ void k_cp(const float* __restrict__ proj_w, float* __restrict__ ws)
{
    int b = blockIdx.x;
    int t = threadIdx.x;                 // 128 threads, one per v
    __shared__ float crow[DDIM];
    const float* ctx = ws + OFF_CTX + (size_t)b * DDIM;
    for (int d = t; d < DDIM; d += 128) crow[d] = ctx[d];
    __syncthreads();
    const float* pr = proj_w + (size_t)t * DDIM;
    float acc = 0.0f;
    for (int d = 0; d < DDIM; ++d) acc += crow[d] * pr[d];
    ws[OFF_CP + (size_t)b * VDIM + t] = acc;
}

// ---------------------------------------------------------------------------
// One-time: convert [W_hh | proj_w] (2176 x 512) to fragment-major f16 hi/lo
// ---------------------------------------------------------------------------
__global__ void k_bsetup(const float* __restrict__ W_hh, const float* __restrict__ proj_w,
                         float* __restrict__ ws)
{
    int n = blockIdx.x;                  // 0..2175
    int t = threadIdx.x;                 // 256
    const float* src = (n < FD) ? (W_hh + (size_t)n * DDIM)
                                : (proj_w + (size_t)(n - FD) * DDIM);
    _Float16* Bhi = (_Float16*)(ws + OFF_BHI);
    _Float16* Blo = (_Float16*)(ws + OFF_BLO);
    for (int k = t; k < DDIM; k += 256)
        split_write(src[k], Bhi, Blo, n, k);
}

// ---------------------------------------------------------------------------
// Persistent time loop. 544 active blocks = 16 row-groups x 34 col-tiles.
// Launched as 640 (padded) so that blk%8 == ct%8: under round-robin
// block->XCD placement each XCD sees <=5 ct slices -> its B-fragment working
// set (~1.25 MB) stays L2-resident. Pure locality heuristic, not correctness.
//
// Cross-block data (G, LC, A-frags) moves through cache-bypass agent atomics;
// barriers are relaxed (no buffer_inv!), so B/E/CP/ctx stay hot in L2.
// c-state lives in registers (thread<->row,d mapping fixed across steps).
//
// __launch_bounds__(256, 3): 3 blocks/CU -> capacity 768 >= 640 launched,
// every block resident -> no barrier deadlock.
// ---------------------------------------------------------------------------
__global__ __launch_bounds__(256, 3) void k_loop(
        const float* __restrict__ proj_b, float* __restrict__ ws,
        float* __restrict__ out, const int* __restrict__ sos_p)
{
    const int blk  = blockIdx.x;         // 0..639
    const int clo  = blk & 7;
    const int rest = blk >> 3;           // 0..79
    const int rt   = rest & 15;          // row-group
    const int chi  = rest >> 4;          // 0..4
    const int ct   = chi * 8 + clo;      // 0..39
    if (ct >= 34) return;                // padding block (96 of them)

    const int tid = threadIdx.x;
    const int w = tid >> 6, lane = tid & 63;
    const int mt  = rt * 4 + w;          // this wave's mtile (0..63)
    const int ntb = ct * 4;              // first of 4 ntiles (0..135)

    unsigned int* bar = &g_bar[rt * 32];

    const v8hf* Ah = (const v8hf*)(ws + OFF_AHI);
    const v8hf* Al = (const v8hf*)(ws + OFF_ALO);
    const v8hf* Bh = (const v8hf*)(ws + OFF_BHI);
    const v8hf* Bl = (const v8hf*)(ws + OFF_BLO);
    _Float16* Ahi16 = (_Float16*)(ws + OFF_AHI);
    _Float16* Alo16 = (_Float16*)(ws + OFF_ALO);
    const int aBase = mt * 16;

    // pointwise ownership (blocks ct<32): row = rt*64 + ct*2 + (tid>>7),
    // d-quad = (tid&127)*4. Fixed across steps -> c-state in registers.
    const int rowSel = tid >> 7;
    const int pw_b   = rt * 64 + ct * 2 + rowSel;
    const int pw_d0  = (tid & 127) * 4;
    float creg[4] = {0.f, 0.f, 0.f, 0.f};

    __shared__ int s_id[2];
    unsigned int phase = 0;

    for (int tau = 0; tau <= 201; ++tau) {
        // tau 0: gates only; 1..200: gates + logits(tau-1); 201: logits(200) only
        const bool doGemm = (tau == 0) ? (ct < 32) : (tau == 201) ? (ct >= 32) : true;
        const int  tout   = (tau >= 1) ? (tau - 1) : -1;

        if (doGemm) {
            v4f acc1[4], acc2[4];
#pragma unroll
            for (int nt = 0; nt < 4; ++nt) {
                acc1[nt] = (v4f){0.f, 0.f, 0.f, 0.f};
                acc2[nt] = (v4f){0.f, 0.f, 0.f, 0.f};
            }

            v8hf ah = co_load_frag(Ah, (aBase + 0) * 64 + lane);
            v8hf al = co_load_frag(Al, (aBase + 0) * 64 + lane);
            v8hf bh[4], bl[4];
#pragma unroll
            for (int nt = 0; nt < 4; ++nt) {
                bh[nt] = Bh[((ntb + nt) * 16 + 0) * 64 + lane];   // normal: L2-warm
                bl[nt] = Bl[((ntb + nt) * 16 + 0) * 64 + lane];
            }

#pragma unroll
            for (int kt = 0; kt < 16; ++kt) {
                v8hf nah, nal, nbh[4], nbl[4];
                if (kt < 15) {
                    int k1 = kt + 1;
                    nah = co_load_frag(Ah, (aBase + k1) * 64 + lane);
                    nal = co_load_frag(Al, (aBase + k1) * 64 + lane);
#pragma unroll
                    for (int nt = 0; nt < 4; ++nt) {
                        nbh[nt] = Bh[((ntb + nt) * 16 + k1) * 64 + lane];
                        nbl[nt] = Bl[((ntb + nt) * 16 + k1) * 64 + lane];
                    }
                }
#pragma unroll
                for (int nt = 0; nt < 4; ++nt) {
                    acc1[nt] = __builtin_amdgcn_mfma_f32_16x16x32_f16(ah, bh[nt], acc1[nt], 0, 0, 0);
                    acc2[nt] = __builtin_amdgcn_mfma_f32_16x16x32_f16(ah, bl[nt], acc2[nt], 0, 0, 0);
                    acc2[nt] = __builtin_amdgcn_mfma_f32_16x16x32_f16(al, bh[nt], acc2[nt], 0, 0, 0);
                }
                if (kt < 15) {
                    ah = nah; al = nal;
#pragma unroll
                    for (int nt = 0; nt < 4; ++nt) { bh[nt] = nbh[nt]; bl[nt] = nbl[nt]; }
                }
            }

            // Epilogue. C/D: col = lane&15, row = (lane>>4)*4 + reg
            int nloc = lane & 15;
            int mrow = mt * 16 + (lane >> 4) * 4;
            if (ntb < 128) {             // gates tiles -> coherent G
                float* g = ws + OFF_G;
#pragma unroll
                for (int nt = 0; nt < 4; ++nt) {
                    int n = (ntb + nt) * 16 + nloc;
#pragma unroll
                    for (int r = 0; r < 4; ++r)
                        co_store_f(&g[(size_t)(mrow + r) * FD + n],
                                   acc1[nt][r] + acc2[nt][r] * INV_LOSCALE);
                }
            } else {                     // logits tiles
#pragma unroll
                for (int nt = 0; nt < 4; ++nt) {
                    int v = (ntb + nt) * 16 + nloc - FD;
#pragma unroll
                    for (int r = 0; r < 4; ++r) {
                        int b = mrow + r;
                        float val = acc1[nt][r] + acc2[nt][r] * INV_LOSCALE;
                        float lg = val - ws[OFF_CP + (size_t)b * VDIM + v] + proj_b[v];
                        if (tout >= 0) {
                            out[((size_t)b * VDIM + v) * TDIM + tout] = lg;  // host-only: normal
                            co_store_f(&ws[OFF_LC + (size_t)b * VDIM + v], lg);
                        }
                    }
                }
            }
        }

        if (tau == 201) break;

        ++phase;
        group_barrier(bar, phase * 34u);     // gates/logits -> pointwise

        // -------- pointwise: blocks ct<32; both rows in parallel (128 thr each)
        if (ct < 32) {
            if (tau >= 1) {
                // wave 0 -> row +0, wave 2 -> row +1 (first-index argmax)
                if ((w & 1) == 0) {
                    const int br = rt * 64 + ct * 2 + (w >> 1);
                    const float* lc = ws + OFF_LC + (size_t)br * VDIM;
                    float bv = co_load_f(lc + lane);
                    int   bi = lane;
                    float v1 = co_load_f(lc + lane + 64);
                    if (v1 > bv) { bv = v1; bi = lane + 64; }
                    for (int off = 32; off > 0; off >>= 1) {
                        float ov = __shfl_down(bv, off);
                        int   oi = __shfl_down(bi, off);
                        if (ov > bv || (ov == bv && oi < bi)) { bv = ov; bi = oi; }
                    }
                    if (lane == 0) s_id[w >> 1] = bi;
                }
            } else if (tid < 2) {
                s_id[tid] = sos_p[0];
            }
            __syncthreads();
            const int id = s_id[rowSel];

            // gates (coherent), E/ctx (normal, L2-warm)
            union GU { u64 u[2]; float f[4]; } gq[4];
            const float* gbase = ws + OFF_G + (size_t)pw_b * FD + pw_d0;
#pragma unroll
            for (int q = 0; q < 4; ++q) {
                const u64* p = (const u64*)(gbase + q * DDIM);
                gq[q].u[0] = co_load_u64(p);
                gq[q].u[1] = co_load_u64(p + 1);
            }
            const float* Erow = ws + OFF_E + (size_t)id * FD + pw_d0;
            v4f ev[4];
#pragma unroll
            for (int q = 0; q < 4; ++q) ev[q] = *(const v4f*)(Erow + q * DDIM);
            const v4f cxv = *(const v4f*)(ws + OFF_CTX + (size_t)pw_b * DDIM + pw_d0);

            _Float16 hh[4], hl[4];
#pragma unroll
            for (int j = 0; j < 4; ++j) {
                float gi = gq[0].f[j] + ev[0][j];
                float gf = gq[1].f[j] + ev[1][j];
                float gg = gq[2].f[j] + ev[2][j];
                float go = gq[3].f[j] + ev[3][j];
                float si = 1.0f / (1.0f + expf(-gi));
                float sf = 1.0f / (1.0f + expf(-gf));
                float so = 1.0f / (1.0f + expf(-go));
                float cn = sf * creg[j] + si * tanhf(gg);
                creg[j] = cn;
                float hn = so * tanhf(cn);
                float av = hn + cxv[j];
                _Float16 h = (_Float16)av;
                hh[j] = h;
                hl[j] = (_Float16)((av - (float)h) * LOSCALE);
            }
            // A-frag write: 4 consecutive k in one 8-run -> one 8B store per array
            int lane_a = (pw_b & 15) | (((pw_d0 >> 3) & 3) << 4);
            size_t idx = ((size_t)((pw_b >> 4) * 16 + (pw_d0 >> 5)) * 64 + lane_a) * 8
                         + (pw_d0 & 7);
            co_store_h4(Ahi16 + idx, hh[0], hh[1], hh[2], hh[3]);
            co_store_h4(Alo16 + idx, hl[0], hl[1], hl[2], hl[3]);
        }

        ++phase;
        group_barrier(bar, phase * 34u);     // A-fragments -> next GEMM
    }
}

extern "C" void kernel_launch(void* const* d_in, const int* in_sizes, int n_in,
                              void* d_out, int out_size, void* d_ws, size_t ws_size,
                              hipStream_t stream)
{
    const float* fm     = (const float*)d_in[0];
    const float* pooled = (const float*)d_in[1];
    const float* gamma  = (const float*)d_in[2];
    const float* beta   = (const float*)d_in[3];
    const float* W_ih   = (const float*)d_in[4];
    const float* W_hh   = (const float*)d_in[5];
    const float* b_ih   = (const float*)d_in[6];
    const float* b_hh   = (const float*)d_in[7];
    const float* embed  = (const float*)d_in[8];
    const float* attn_w = (const float*)d_in[9];
    // d_in[10] = attn_b : provably unused (softmax shift invariance)
    const float* proj_w = (const float*)d_in[11];
    const float* proj_b = (const float*)d_in[12];
    const int*   sos_p  = (const int*)d_in[13];

    float* ws  = (float*)d_ws;
    float* out = (float*)d_out;

    k_init<<<BDIM, 256, 0, stream>>>(fm, pooled, gamma, beta, attn_w, ws);
    k_E<<<FD, 256, 0, stream>>>(embed, W_ih, b_ih, b_hh, ws);
    k_cp<<<BDIM, 128, 0, stream>>>(proj_w, ws);
    k_bsetup<<<FD + VDIM, 256, 0, stream>>>(W_hh, proj_w, ws);

    // Entire 201-step recurrence in ONE persistent kernel.
    // 640 = padded grid for the blk%8 == ct%8 L2-locality swizzle.
    k_loop<<<dim3(640), 256, 0, stream>>>(proj_b, ws, out, sos_p);
}

// Round 3
// 17517.683 us; speedup vs baseline: 1.4857x; 1.1197x over previous
//
#include <hip/hip_runtime.h>
#include <math.h>

#define BDIM 1024
#define DDIM 512
#define VDIM 128
#define TDIM 201
#define FD   2048            // 4*D
#define LN_EPS 1e-5f
#define LOSCALE 4096.0f
#define INV_LOSCALE (1.0f/4096.0f)

// ws layout in floats
#define OFF_C   0            // (unused by loop now; kept for k_init compat)
#define OFF_CTX 524288       // B*D      context (constant across steps)   [read-only in loop]
#define OFF_E   1048576      // V*FD     E = embed @ W_ih^T + b_ih + b_hh  [read-only in loop]
#define OFF_CP  1310720      // B*V      ctx @ proj^T                      [read-only in loop]
#define OFF_ID  1441792      // B ints   argmax ids                        [coherent]
#define OFF_AHI 3670016      // A hi frags                                 [coherent]
#define OFF_ALO 3932160      // A lo frags (scaled by 4096)                [coherent]
#define OFF_BHI 4194304      // B hi frags                                 [read-only in loop]
#define OFF_BLO 4751360      // B lo frags                                 [read-only in loop]

typedef _Float16 v8hf __attribute__((ext_vector_type(8)));
typedef float    v4f  __attribute__((ext_vector_type(4)));
typedef unsigned long long u64;

#define AGENT __HIP_MEMORY_SCOPE_AGENT
#define RLX   __ATOMIC_RELAXED

// Per-row-group barrier counters (16 groups, 128 B apart). Reset by k_init.
__device__ unsigned int g_bar[16 * 32];

// Relaxed agent-scope atomics -> sc0+sc1 load/store: bypass L1/L2, coherent at
// L3. No fences anywhere -> no buffer_inv -> read-only L2 sets stay warm.
__device__ __forceinline__ u64 co_load_u64(const void* p) {
    return __hip_atomic_load((u64*)p, RLX, AGENT);
}
__device__ __forceinline__ void co_store_u64(void* p, u64 v) {
    __hip_atomic_store((u64*)p, v, RLX, AGENT);
}
__device__ __forceinline__ int co_load_int(const void* p) {
    return __hip_atomic_load((int*)p, RLX, AGENT);
}
__device__ __forceinline__ void co_store_int(void* p, int v) {
    __hip_atomic_store((int*)p, v, RLX, AGENT);
}

// Group barrier across the 9 blocks of one row-group. Producer ordering: the
// __syncthreads() drains vmcnt per thread before thread 0's add. Consumer
// ordering: loads issue after the dependent poll + compiler memory barrier.
// Bounded spin -> logic bugs fail fast (wrong results), never harness-hang.
__device__ __forceinline__ void group_barrier(unsigned int* bar, unsigned int target)
{
    __syncthreads();
    if (threadIdx.x == 0) {
        __hip_atomic_fetch_add(bar, 1u, RLX, AGENT);
        unsigned int spins = 0;
        while (__hip_atomic_load(bar, RLX, AGENT) < target) {
            __builtin_amdgcn_s_sleep(1);
            if (++spins > (1u << 20)) break;
        }
    }
    __syncthreads();
    asm volatile("" ::: "memory");
    __builtin_amdgcn_sched_barrier(0);
}

// Fragment-major layouts (16x16x32 f16 MFMA):
//   A: lane l holds A[m = mt*16 + (l&15)][k = kt*32 + (l>>4)*8 + j]
//      Afrag[((mt*16 + kt)*64 + l)*8 + j]
//   B: lane l holds W[n = nt*16 + (l&15)][k = ...]
//   C/D: col = lane&15, row = (lane>>4)*4 + reg
__device__ __forceinline__ void split_write(float x, _Float16* hiArr, _Float16* loArr,
                                            int row, int k)
{
    _Float16 hi = (_Float16)x;
    _Float16 lo = (_Float16)((x - (float)hi) * LOSCALE);
    int lane = (row & 15) | (((k >> 3) & 3) << 4);
    size_t idx = ((size_t)((row >> 4) * 16 + (k >> 5)) * 64 + lane) * 8 + (k & 7);
    hiArr[idx] = hi;
    loArr[idx] = lo;
}

// ---------------------------------------------------------------------------
// init: LayerNorm(pooled) -> h0 ; softmax(fm@wf) -> context ; A0 fragments.
// ---------------------------------------------------------------------------
__global__ void k_init(const float* __restrict__ fm, const float* __restrict__ pooled,
                       const float* __restrict__ gamma, const float* __restrict__ beta,
                       const float* __restrict__ attn_w, float* __restrict__ ws)
{
    int b = blockIdx.x;
    int t = threadIdx.x;                 // 256 threads
    __shared__ float red[256];
    __shared__ float s_sc[49];
    __shared__ float s_aw[49];
    __shared__ float s_ctx[DDIM];

    if (b == 0 && t < 16) g_bar[t * 32] = 0u;   // barrier reset

    const float* prow = pooled + (size_t)b * DDIM;
    float x0 = prow[t], x1 = prow[t + 256];
    red[t] = x0 + x1;
    __syncthreads();
    for (int s = 128; s > 0; s >>= 1) { if (t < s) red[t] += red[t + s]; __syncthreads(); }
    float mu = red[0] * (1.0f / DDIM);
    __syncthreads();
    float d0 = x0 - mu, d1 = x1 - mu;
    red[t] = d0 * d0 + d1 * d1;
    __syncthreads();
    for (int s = 128; s > 0; s >>= 1) { if (t < s) red[t] += red[t + s]; __syncthreads(); }
    float rstd = rsqrtf(red[0] * (1.0f / DDIM) + LN_EPS);

    float h0 = d0 * rstd * gamma[t]       + beta[t];
    float h1 = d1 * rstd * gamma[t + 256] + beta[t + 256];

    // scores[k] = sum_d fm[b,d,k] * wf[d]   (fm layout: (B, D, 49))
    if (t < 49) {
        const float* base = fm + (size_t)b * DDIM * 49 + t;
        float acc = 0.0f;
        for (int d = 0; d < DDIM; ++d) acc += base[(size_t)d * 49] * attn_w[d];
        s_sc[t] = acc;
    }
    __syncthreads();
    if (t == 0) {
        float mx = s_sc[0];
        for (int k = 1; k < 49; ++k) mx = fmaxf(mx, s_sc[k]);
        float sum = 0.0f;
        for (int k = 0; k < 49; ++k) { float e = expf(s_sc[k] - mx); s_aw[k] = e; sum += e; }
        float inv = 1.0f / sum;
        for (int k = 0; k < 49; ++k) s_aw[k] *= inv;
    }
    __syncthreads();

    float* ctx = ws + OFF_CTX + (size_t)b * DDIM;
    for (int d = t; d < DDIM; d += 256) {
        const float* base = fm + ((size_t)b * DDIM + d) * 49;
        float acc = 0.0f;
        for (int k = 0; k < 49; ++k) acc += s_aw[k] * base[k];
        ctx[d] = acc;
        s_ctx[d] = acc;
    }
    __syncthreads();

    _Float16* Ahi = (_Float16*)(ws + OFF_AHI);
    _Float16* Alo = (_Float16*)(ws + OFF_ALO);
    split_write(h0 + s_ctx[t],       Ahi, Alo, b, t);
    split_write(h1 + s_ctx[t + 256], Ahi, Alo, b, t + 256);
}

// ---------------------------------------------------------------------------
// E[v, n] = sum_d embed[v,d] * W_ih[n,d] + b_ih[n] + b_hh[n]   (128 x 2048)
// ---------------------------------------------------------------------------
__global__ void k_E(const float* __restrict__ embed, const float* __restrict__ W_ih,
                    const float* __restrict__ b_ih, const float* __restrict__ b_hh,
                    float* __restrict__ ws)
{
    int n = blockIdx.x;
    int t = threadIdx.x;                 // 256 threads
    __shared__ float wrow[DDIM];
    wrow[t]       = W_ih[(size_t)n * DDIM + t];
    wrow[t + 256] = W_ih[(size_t)n * DDIM + t + 256];
    __syncthreads();
    if (t < VDIM) {
        const float* er = embed + (size_t)t * DDIM;
        float acc = 0.0f;
        for (int d = 0; d < DDIM; ++d) acc += er[d] * wrow[d];
        ws[OFF_E + (size_t)t * FD + n] = acc + b_ih[n] + b_hh[n];
    }
}

// ---------------------------------------------------------------------------
// ctxproj[b, v] = sum_d ctx[b,d] * proj_w[v,d]
// ---------------------------------------------------------------------------
__global__ void k_cp(const float* __restrict__ proj_w, float* __restrict__ ws)
{
    int b = blockIdx.x;
    int t = threadIdx.x;                 // 128 threads, one per v
    __shared__ float crow[DDIM];
    const float* ctx = ws + OFF_CTX + (size_t)b * DDIM;
    for (int d = t; d < DDIM; d += 128) crow[d] = ctx[d];
    __syncthreads();
    const float* pr = proj_w + (size_t)t * DDIM;
    float acc = 0.0f;
    for (int d = 0; d < DDIM; ++d) acc += crow[d] * pr[d];
    ws[OFF_CP + (size_t)b * VDIM + t] = acc;
}

// ---------------------------------------------------------------------------
// One-time: [W_hh | proj_w] (2176 x 512) -> fragment-major f16 hi/lo
// ---------------------------------------------------------------------------
__global__ void k_bsetup(const float* __restrict__ W_hh, const float* __restrict__ proj_w,
                         float* __restrict__ ws)
{
    int n = blockIdx.x;                  // 0..2175
    int t = threadIdx.x;                 // 256
    const float* src = (n < FD) ? (W_hh + (size_t)n * DDIM)
                                : (proj_w + (size_t)(n - FD) * DDIM);
    _Float16* Bhi = (_Float16*)(ws + OFF_BHI);
    _Float16* Blo = (_Float16*)(ws + OFF_BLO);
    for (int k = t; k < DDIM; k += 256)
        split_write(src[k], Bhi, Blo, n, k);
}

// ---------------------------------------------------------------------------
// Batched A stage: wave's 32 bypass loads issued back-to-back (one latency
// exposure), then LDS writes. Wave pair (w, w+4) shares mtile m: low half
// stages kt 0..7, high half kt 8..15.
// ---------------------------------------------------------------------------
__device__ __forceinline__ void stage_A(const float* __restrict__ ws,
                                        unsigned char* smem,
                                        int mt, int m, int hiW, int lane)
{
    const u64* Ah = (const u64*)(ws + OFF_AHI);
    const u64* Al = (const u64*)(ws + OFF_ALO);
    u64 st[32];
#pragma unroll
    for (int k8 = 0; k8 < 8; ++k8) {
        int kt = hiW * 8 + k8;
        size_t fi = ((size_t)(mt * 16 + kt) * 64 + lane) * 2;
        st[k8 * 4 + 0] = co_load_u64(Ah + fi);
        st[k8 * 4 + 1] = co_load_u64(Ah + fi + 1);
        st[k8 * 4 + 2] = co_load_u64(Al + fi);
        st[k8 * 4 + 3] = co_load_u64(Al + fi + 1);
    }
#pragma unroll
    for (int k8 = 0; k8 < 8; ++k8) {
        int kt = hiW * 8 + k8;
        u64* ph = (u64*)(smem + m * 32768 + kt * 2048 + lane * 16);
        ph[0] = st[k8 * 4 + 0]; ph[1] = st[k8 * 4 + 1];
        u64* pl = (u64*)(smem + m * 32768 + kt * 2048 + 1024 + lane * 16);
        pl[0] = st[k8 * 4 + 2]; pl[1] = st[k8 * 4 + 3];
    }
    __syncthreads();
}

// 4-ntile GEMM over all 16 kt: A from LDS, B from L2-warm global, split MFMA.
__device__ __forceinline__ void gemm4(const unsigned char* smem, int m, int lane,
                                      const v8hf* __restrict__ Bh,
                                      const v8hf* __restrict__ Bl,
                                      int n0, int n1, int n2, int n3,
                                      v4f a1[4], v4f a2[4])
{
    const int nts[4] = {n0, n1, n2, n3};
    v8hf bh[4], bl[4];
#pragma unroll
    for (int t = 0; t < 4; ++t) {
        bh[t] = Bh[(nts[t] * 16 + 0) * 64 + lane];
        bl[t] = Bl[(nts[t] * 16 + 0) * 64 + lane];
    }
#pragma unroll
    for (int kt = 0; kt < 16; ++kt) {
        v8hf nbh[4], nbl[4];
        if (kt < 15) {
#pragma unroll
            for (int t = 0; t < 4; ++t) {
                nbh[t] = Bh[(nts[t] * 16 + kt + 1) * 64 + lane];
                nbl[t] = Bl[(nts[t] * 16 + kt + 1) * 64 + lane];
            }
        }
        v8hf ah = *(const v8hf*)(smem + m * 32768 + kt * 2048 + lane * 16);
        v8hf al = *(const v8hf*)(smem + m * 32768 + kt * 2048 + 1024 + lane * 16);
#pragma unroll
        for (int t = 0; t < 4; ++t) {
            a1[t] = __builtin_amdgcn_mfma_f32_16x16x32_f16(ah, bh[t], a1[t], 0, 0, 0);
            a2[t] = __builtin_amdgcn_mfma_f32_16x16x32_f16(ah, bl[t], a2[t], 0, 0, 0);
            a2[t] = __builtin_amdgcn_mfma_f32_16x16x32_f16(al, bh[t], a2[t], 0, 0, 0);
        }
        if (kt < 15) {
#pragma unroll
            for (int t = 0; t < 4; ++t) { bh[t] = nbh[t]; bl[t] = nbl[t]; }
        }
    }
}

// ---------------------------------------------------------------------------
// Persistent loop. Grid 144 = 16 rg x (8 gates blocks + 1 logits block),
// 512 threads (8 waves = 4 wave-pairs, pair <-> mtile).
//
// Gates block j (blk = rt*8 + j, so blk%8 == j for per-XCD B locality):
//   ntiles {q, q+32, q+64, q+96} for q in {4j..4j+3} -> each lane's acc holds
//   (i,f,g,o) for one d and 4 rows -> LSTM pointwise IN REGISTERS (no G!).
//   c-state in registers; writes only its 16 KB A-frag slice (bypass).
// Logits block (blk = 128 + rt): ntiles 128..135, argmax in-block, publishes
//   id[] (4 KB/step) via bypass.
// Cross-block bytes/step: A-stage 9 x 128 KB x 16rg = 18 MB (was 96 MB).
// ---------------------------------------------------------------------------
__global__ __launch_bounds__(512) void k_loop(
        const float* __restrict__ proj_b, float* __restrict__ ws,
        float* __restrict__ out, const int* __restrict__ sos_p)
{
    const int blk = blockIdx.x;
    int rt, j;
    if (blk < 128) { rt = blk >> 3; j = blk & 7; }
    else           { rt = blk - 128; j = 8; }
    const bool isLog = (j == 8);

    const int tid = threadIdx.x;
    const int w = tid >> 6, lane = tid & 63;
    const int m = w & 3, hiW = w >> 2;
    const int mt = rt * 4 + m;
    const int l15 = lane & 15, l4 = lane >> 4;

    __shared__ __align__(16) unsigned char smem[131072];

    unsigned int* bar = &g_bar[rt * 32];
    const v8hf* Bh = (const v8hf*)(ws + OFF_BHI);
    const v8hf* Bl = (const v8hf*)(ws + OFF_BLO);
    int* idbuf = (int*)(ws + OFF_ID);
    const int qb = j * 4 + hiW * 2;      // gates blocks only

    float ctxreg[2][4], creg[2][4];      // gates
    float cpv[4][4], pbv[4];             // logits
    if (!isLog) {
#pragma unroll
        for (int p = 0; p < 2; ++p) {
            int d = (qb + p) * 16 + l15;
#pragma unroll
            for (int r = 0; r < 4; ++r) {
                int row = mt * 16 + l4 * 4 + r;
                ctxreg[p][r] = ws[OFF_CTX + (size_t)row * DDIM + d];
                creg[p][r] = 0.0f;
            }
        }
    } else {
#pragma unroll
        for (int n = 0; n < 4; ++n) {
            int v = (hiW * 4 + n) * 16 + l15;
            pbv[n] = proj_b[v];
#pragma unroll
            for (int r = 0; r < 4; ++r) {
                int row = mt * 16 + l4 * 4 + r;
                cpv[n][r] = ws[OFF_CP + (size_t)row * VDIM + v];
            }
        }
    }
    const int sosv = sos_p[0];

    float gv[2][4][4];                   // [pass][gate i/f/g/o][r]
    unsigned int tgt = 0;

    for (int tau = 0; tau <= 200; ++tau) {
        stage_A(ws, smem, mt, m, hiW, lane);

        if (!isLog) {
#pragma unroll
            for (int p = 0; p < 2; ++p) {
                int q = qb + p;
                v4f a1[4], a2[4];
#pragma unroll
                for (int t = 0; t < 4; ++t) {
                    a1[t] = (v4f){0.f, 0.f, 0.f, 0.f};
                    a2[t] = (v4f){0.f, 0.f, 0.f, 0.f};
                }
                gemm4(smem, m, lane, Bh, Bl, q, q + 32, q + 64, q + 96, a1, a2);
#pragma unroll
                for (int t = 0; t < 4; ++t)
#pragma unroll
                    for (int r = 0; r < 4; ++r)
                        gv[p][t][r] = a1[t][r] + a2[t][r] * INV_LOSCALE;
            }
        } else if (tau >= 1) {
            v4f a1[4], a2[4];
#pragma unroll
            for (int t = 0; t < 4; ++t) {
                a1[t] = (v4f){0.f, 0.f, 0.f, 0.f};
                a2[t] = (v4f){0.f, 0.f, 0.f, 0.f};
            }
            int n0 = 128 + hiW * 4;
            gemm4(smem, m, lane, Bh, Bl, n0, n0 + 1, n0 + 2, n0 + 3, a1, a2);

            float lgv[4][4];
#pragma unroll
            for (int t = 0; t < 4; ++t) {
                int v = (hiW * 4 + t) * 16 + l15;
#pragma unroll
                for (int r = 0; r < 4; ++r) {
                    float val = a1[t][r] + a2[t][r] * INV_LOSCALE;
                    float lg = (val - cpv[t][r]) + pbv[t];
                    lgv[t][r] = lg;
                    int row = mt * 16 + l4 * 4 + r;
                    out[((size_t)row * VDIM + v) * TDIM + (tau - 1)] = lg;
                }
            }
            // first-index argmax over this wave's 64 cols
            float bvr[4]; int bir[4];
#pragma unroll
            for (int r = 0; r < 4; ++r) {
                float bv = lgv[0][r]; int bi = (hiW * 4) * 16 + l15;
#pragma unroll
                for (int t = 1; t < 4; ++t) {
                    int v = (hiW * 4 + t) * 16 + l15;
                    if (lgv[t][r] > bv) { bv = lgv[t][r]; bi = v; }
                }
#pragma unroll
                for (int off = 1; off <= 8; off <<= 1) {
                    float ov = __shfl_xor(bv, off, 64);
                    int   oi = __shfl_xor(bi, off, 64);
                    if (ov > bv || (ov == bv && oi < bi)) { bv = ov; bi = oi; }
                }
                bvr[r] = bv; bir[r] = bi;
            }
            // combine the two wave halves (hi half = cols 64..127; tie -> low)
            if (hiW == 1 && l15 == 0) {
#pragma unroll
                for (int r = 0; r < 4; ++r) {
                    int rl = l4 * 4 + r;
                    *(float*)(smem + m * 32768 + 4096 + rl * 8)     = bvr[r];
                    *(int*)  (smem + m * 32768 + 4096 + rl * 8 + 4) = bir[r];
                }
            }
            __syncthreads();
            if (hiW == 0 && l15 == 0) {
#pragma unroll
                for (int r = 0; r < 4; ++r) {
                    int rl = l4 * 4 + r;
                    float v1 = *(float*)(smem + m * 32768 + 4096 + rl * 8);
                    int   i1 = *(int*)  (smem + m * 32768 + 4096 + rl * 8 + 4);
                    int fin = (v1 > bvr[r]) ? i1 : bir[r];
                    co_store_int(idbuf + mt * 16 + rl, fin);
                }
            }
        }

        tgt += 9; group_barrier(bar, tgt);   // gemm/argmax -> pointwise

        if (!isLog) {
            int idv[4];
#pragma unroll
            for (int r = 0; r < 4; ++r) {
                int row = mt * 16 + l4 * 4 + r;
                idv[r] = (tau == 0) ? sosv : co_load_int(idbuf + row);
            }
#pragma unroll
            for (int p = 0; p < 2; ++p) {
                int d = (qb + p) * 16 + l15;
                int sel3 = (d >> 3) & 3;
                int elem = l15 & 7;
#pragma unroll
                for (int r = 0; r < 4; ++r) {
                    const float* er = ws + OFF_E + (size_t)idv[r] * FD;
                    float gi = gv[p][0][r] + er[d];
                    float gf = gv[p][1][r] + er[d + 512];
                    float gg = gv[p][2][r] + er[d + 1024];
                    float go = gv[p][3][r] + er[d + 1536];
                    float si = 1.0f / (1.0f + expf(-gi));
                    float sf = 1.0f / (1.0f + expf(-gf));
                    float so = 1.0f / (1.0f + expf(-go));
                    float cn = sf * creg[p][r] + si * tanhf(gg);
                    creg[p][r] = cn;
                    float hn = so * tanhf(cn);
                    float av = hn + ctxreg[p][r];
                    _Float16 hh = (_Float16)av;
                    _Float16 hl = (_Float16)((av - (float)hh) * LOSCALE);
                    int la = (l4 * 4 + r) | (sel3 << 4);
                    *(unsigned short*)(smem + m * 32768 + hiW * 2048 + la * 16 + elem * 2)
                        = *(unsigned short*)&hh;
                    *(unsigned short*)(smem + m * 32768 + hiW * 2048 + 1024 + la * 16 + elem * 2)
                        = *(unsigned short*)&hl;
                }
            }
            __syncthreads();
            // cooperative coalesced A-slice store: 16 KB (4 mt x 2 kt x hi/lo)
            {
                int m2 = tid >> 7, rr2 = tid & 127;
                int ktl2 = rr2 >> 6, s2 = (rr2 >> 5) & 1, la2 = (rr2 & 31) * 2;
                const u64* src = (const u64*)(smem + m2 * 32768 + ktl2 * 2048
                                              + s2 * 1024 + la2 * 16);
                int ktg = 2 * j + ktl2;
                u64* dst = (u64*)(ws + (s2 ? OFF_ALO : OFF_AHI))
                         + ((size_t)((rt * 4 + m2) * 16 + ktg) * 64 + la2) * 2;
#pragma unroll
                for (int z = 0; z < 4; ++z) co_store_u64(dst + z, src[z]);
            }
        }

        tgt += 9; group_barrier(bar, tgt);   // new A published -> next stage
    }

    if (isLog) {
        // final logits (t = 200) from A_201; no argmax needed
        stage_A(ws, smem, mt, m, hiW, lane);
        v4f a1[4], a2[4];
#pragma unroll
        for (int t = 0; t < 4; ++t) {
            a1[t] = (v4f){0.f, 0.f, 0.f, 0.f};
            a2[t] = (v4f){0.f, 0.f, 0.f, 0.f};
        }
        int n0 = 128 + hiW * 4;
        gemm4(smem, m, lane, Bh, Bl, n0, n0 + 1, n0 + 2, n0 + 3, a1, a2);
#pragma unroll
        for (int t = 0; t < 4; ++t) {
            int v = (hiW * 4 + t) * 16 + l15;
#pragma unroll
            for (int r = 0; r < 4; ++r) {
                float val = a1[t][r] + a2[t][r] * INV_LOSCALE;
                float lg = (val - cpv[t][r]) + pbv[t];
                int row = mt * 16 + l4 * 4 + r;
                out[((size_t)row * VDIM + v) * TDIM + 200] = lg;
            }
        }
    }
}

extern "C" void kernel_launch(void* const* d_in, const int* in_sizes, int n_in,
                              void* d_out, int out_size, void* d_ws, size_t ws_size,
                              hipStream_t stream)
{
    const float* fm     = (const float*)d_in[0];
    const float* pooled = (const float*)d_in[1];
    const float* gamma  = (const float*)d_in[2];
    const float* beta   = (const float*)d_in[3];
    const float* W_ih   = (const float*)d_in[4];
    const float* W_hh   = (const float*)d_in[5];
    const float* b_ih   = (const float*)d_in[6];
    const float* b_hh   = (const float*)d_in[7];
    const float* embed  = (const float*)d_in[8];
    const float* attn_w = (const float*)d_in[9];
    // d_in[10] = attn_b : provably unused (softmax shift invariance)
    const float* proj_w = (const float*)d_in[11];
    const float* proj_b = (const float*)d_in[12];
    const int*   sos_p  = (const int*)d_in[13];

    float* ws  = (float*)d_ws;
    float* out = (float*)d_out;

    k_init<<<BDIM, 256, 0, stream>>>(fm, pooled, gamma, beta, attn_w, ws);
    k_E<<<FD, 256, 0, stream>>>(embed, W_ih, b_ih, b_hh, ws);
    k_cp<<<BDIM, 128, 0, stream>>>(proj_w, ws);
    k_bsetup<<<FD + VDIM, 256, 0, stream>>>(W_hh, proj_w, ws);

    // Entire 201-step recurrence in ONE persistent kernel.
    // 144 blocks = 16 row-groups x (8 gates + 1 logits), 512 thr, 128 KB LDS
    // -> 1 block/CU, all resident (144 <= 256), group barriers per rg.
    k_loop<<<dim3(144), 512, 0, stream>>>(proj_b, ws, out, sos_p);
}

// Round 4
// 11786.989 us; speedup vs baseline: 2.2081x; 1.4862x over previous
//
#include <hip/hip_runtime.h>
#include <math.h>

#define BDIM 1024
#define DDIM 512
#define VDIM 128
#define TDIM 201
#define FD   2048            // 4*D
#define LN_EPS 1e-5f
#define LOSCALE 4096.0f
#define INV_LOSCALE (1.0f/4096.0f)

// ws layout in floats
#define OFF_CTX 524288       // B*D      context (constant)            [read-only in loop]
#define OFF_E   1048576      // V*FD     E = embed@W_ih^T + b_ih+b_hh  [read-only in loop]
#define OFF_CP  1310720      // B*V      ctx @ proj^T                  [read-only in loop]
#define OFF_PART 1441792     // 1024*8 u64 partial argmax pairs        [group-shared]
#define OFF_AHI 3670016      // A hi frags                             [group-shared]
#define OFF_ALO 3932160      // A lo frags (scaled by 4096)            [group-shared]
#define OFF_BHI 4194304      // B hi frags                             [read-only in loop]
#define OFF_BLO 4751360      // B lo frags                             [read-only in loop]

typedef _Float16 v8hf __attribute__((ext_vector_type(8)));
typedef float    v4f  __attribute__((ext_vector_type(4)));
typedef unsigned long long u64;

#define AGENT __HIP_MEMORY_SCOPE_AGENT
#define RLX   __ATOMIC_RELAXED

// 32 group barriers (128 B apart) + rendezvous counter + placement map.
// All reset by k_init (stream-ordered before k_loop) -> replay-safe.
__device__ unsigned int g_bar[32 * 32];
__device__ unsigned int g_cnt;
__device__ int g_xcd[256];

// ---------------------------------------------------------------------------
// Group-shared memory ops. fast (intra-XCD group): producer plain store
// (write-through to the XCD's L2), consumer sc0 load (bypass L1, hit shared
// L2). slow (cross-XCD group): sc0 sc1 both sides (bypass L1+L2, coherent at
// L3) -- the semantics rounds 2/3 validated. NO cache-inv fences anywhere.
// ---------------------------------------------------------------------------
__device__ __forceinline__ u64 ld8_co(const void* p, bool l3) {
    u64 r;
    if (l3) asm volatile("global_load_dwordx2 %0, %1, off sc0 sc1" : "=v"(r) : "v"(p) : "memory");
    else    asm volatile("global_load_dwordx2 %0, %1, off sc0"     : "=v"(r) : "v"(p) : "memory");
    asm volatile("s_waitcnt vmcnt(0)" ::: "memory");
    __builtin_amdgcn_sched_barrier(0);
    return r;
}
__device__ __forceinline__ void st8_co(void* p, u64 v, bool l3) {
    if (l3) asm volatile("global_store_dwordx2 %0, %1, off sc0 sc1" :: "v"(p), "v"(v) : "memory");
    else    *(volatile u64*)p = v;
}
__device__ __forceinline__ void st16_co(void* p, v4f v, bool l3) {
    if (l3) asm volatile("global_store_dwordx4 %0, %1, off sc0 sc1" :: "v"(p), "v"(v) : "memory");
    else    *(volatile v4f*)p = v;
}

// Group barrier (8 blocks). Explicit vmcnt drain covers inline-asm stores the
// compiler can't track; L3 (agent) atomics work for both paths. Bounded spin:
// logic bugs fail fast (wrong results), never harness-hang.
__device__ __forceinline__ void group_barrier(unsigned int* bar, unsigned int target)
{
    asm volatile("s_waitcnt vmcnt(0)" ::: "memory");
    __syncthreads();
    if (threadIdx.x == 0) {
        __hip_atomic_fetch_add(bar, 1u, RLX, AGENT);
        unsigned int spins = 0;
        while (__hip_atomic_load(bar, RLX, AGENT) < target) {
            __builtin_amdgcn_s_sleep(1);
            if (++spins > (1u << 20)) break;
        }
    }
    __syncthreads();
    asm volatile("" ::: "memory");
    __builtin_amdgcn_sched_barrier(0);
}

// Fragment-major layouts (16x16x32 f16 MFMA):
//   A: lane l holds A[m=mt*16+(l&15)][k=kt*32+(l>>4)*8+j] at
//      byte ((mt*16+kt)*64 + l)*16 in AHI/ALO
//   B: same for W rows; C/D: col=lane&15, row=(lane>>4)*4+reg
__device__ __forceinline__ void split_write(float x, _Float16* hiArr, _Float16* loArr,
                                            int row, int k)
{
    _Float16 hi = (_Float16)x;
    _Float16 lo = (_Float16)((x - (float)hi) * LOSCALE);
    int lane = (row & 15) | (((k >> 3) & 3) << 4);
    size_t idx = ((size_t)((row >> 4) * 16 + (k >> 5)) * 64 + lane) * 8 + (k & 7);
    hiArr[idx] = hi;
    loArr[idx] = lo;
}

// ---------------------------------------------------------------------------
// init: LayerNorm(pooled)->h0 ; softmax(fm@wf)->context ; A0 fragments;
// resets barriers + rendezvous counter.
// ---------------------------------------------------------------------------
__global__ void k_init(const float* __restrict__ fm, const float* __restrict__ pooled,
                       const float* __restrict__ gamma, const float* __restrict__ beta,
                       const float* __restrict__ attn_w, float* __restrict__ ws)
{
    int b = blockIdx.x;
    int t = threadIdx.x;                 // 256 threads
    __shared__ float red[256];
    __shared__ float s_sc[49];
    __shared__ float s_aw[49];
    __shared__ float s_ctx[DDIM];

    if (b == 0) {
        if (t < 32) g_bar[t * 32] = 0u;
        if (t == 32) g_cnt = 0u;
    }

    const float* prow = pooled + (size_t)b * DDIM;
    float x0 = prow[t], x1 = prow[t + 256];
    red[t] = x0 + x1;
    __syncthreads();
    for (int s = 128; s > 0; s >>= 1) { if (t < s) red[t] += red[t + s]; __syncthreads(); }
    float mu = red[0] * (1.0f / DDIM);
    __syncthreads();
    float d0 = x0 - mu, d1 = x1 - mu;
    red[t] = d0 * d0 + d1 * d1;
    __syncthreads();
    for (int s = 128; s > 0; s >>= 1) { if (t < s) red[t] += red[t + s]; __syncthreads(); }
    float rstd = rsqrtf(red[0] * (1.0f / DDIM) + LN_EPS);

    float h0 = d0 * rstd * gamma[t]       + beta[t];
    float h1 = d1 * rstd * gamma[t + 256] + beta[t + 256];

    if (t < 49) {
        const float* base = fm + (size_t)b * DDIM * 49 + t;
        float acc = 0.0f;
        for (int d = 0; d < DDIM; ++d) acc += base[(size_t)d * 49] * attn_w[d];
        s_sc[t] = acc;
    }
    __syncthreads();
    if (t == 0) {
        float mx = s_sc[0];
        for (int k = 1; k < 49; ++k) mx = fmaxf(mx, s_sc[k]);
        float sum = 0.0f;
        for (int k = 0; k < 49; ++k) { float e = expf(s_sc[k] - mx); s_aw[k] = e; sum += e; }
        float inv = 1.0f / sum;
        for (int k = 0; k < 49; ++k) s_aw[k] *= inv;
    }
    __syncthreads();

    float* ctx = ws + OFF_CTX + (size_t)b * DDIM;
    for (int d = t; d < DDIM; d += 256) {
        const float* base = fm + ((size_t)b * DDIM + d) * 49;
        float acc = 0.0f;
        for (int k = 0; k < 49; ++k) acc += s_aw[k] * base[k];
        ctx[d] = acc;
        s_ctx[d] = acc;
    }
    __syncthreads();

    _Float16* Ahi = (_Float16*)(ws + OFF_AHI);
    _Float16* Alo = (_Float16*)(ws + OFF_ALO);
    split_write(h0 + s_ctx[t],       Ahi, Alo, b, t);
    split_write(h1 + s_ctx[t + 256], Ahi, Alo, b, t + 256);
}

// ---------------------------------------------------------------------------
// E[v,n] = embed[v,:] . W_ih[n,:] + b_ih[n] + b_hh[n]   (128 x 2048)
// ---------------------------------------------------------------------------
__global__ void k_E(const float* __restrict__ embed, const float* __restrict__ W_ih,
                    const float* __restrict__ b_ih, const float* __restrict__ b_hh,
                    float* __restrict__ ws)
{
    int n = blockIdx.x;
    int t = threadIdx.x;
    __shared__ float wrow[DDIM];
    wrow[t]       = W_ih[(size_t)n * DDIM + t];
    wrow[t + 256] = W_ih[(size_t)n * DDIM + t + 256];
    __syncthreads();
    if (t < VDIM) {
        const float* er = embed + (size_t)t * DDIM;
        float acc = 0.0f;
        for (int d = 0; d < DDIM; ++d) acc += er[d] * wrow[d];
        ws[OFF_E + (size_t)t * FD + n] = acc + b_ih[n] + b_hh[n];
    }
}

__global__ void k_cp(const float* __restrict__ proj_w, float* __restrict__ ws)
{
    int b = blockIdx.x;
    int t = threadIdx.x;                 // 128
    __shared__ float crow[DDIM];
    const float* ctx = ws + OFF_CTX + (size_t)b * DDIM;
    for (int d = t; d < DDIM; d += 128) crow[d] = ctx[d];
    __syncthreads();
    const float* pr = proj_w + (size_t)t * DDIM;
    float acc = 0.0f;
    for (int d = 0; d < DDIM; ++d) acc += crow[d] * pr[d];
    ws[OFF_CP + (size_t)b * VDIM + t] = acc;
}

__global__ void k_bsetup(const float* __restrict__ W_hh, const float* __restrict__ proj_w,
                         float* __restrict__ ws)
{
    int n = blockIdx.x;                  // 0..2175
    int t = threadIdx.x;                 // 256
    const float* src = (n < FD) ? (W_hh + (size_t)n * DDIM)
                                : (proj_w + (size_t)(n - FD) * DDIM);
    _Float16* Bhi = (_Float16*)(ws + OFF_BHI);
    _Float16* Blo = (_Float16*)(ws + OFF_BLO);
    for (int k = t; k < DDIM; k += 256)
        split_write(src[k], Bhi, Blo, n, k);
}

// 16-kt GEMM sweep: A from LDS, B from (L2-warm) global, depth-1 B prefetch.
template<int NT>
__device__ __forceinline__ void gemmN(const unsigned char* aLds, int lane,
                                      const v8hf* __restrict__ Bh,
                                      const v8hf* __restrict__ Bl,
                                      const int* nts, v4f* a1, v4f* a2)
{
    v8hf bh[NT], bl[NT];
#pragma unroll
    for (int tt = 0; tt < NT; ++tt) {
        bh[tt] = Bh[((size_t)nts[tt] * 16 + 0) * 64 + lane];
        bl[tt] = Bl[((size_t)nts[tt] * 16 + 0) * 64 + lane];
    }
#pragma unroll
    for (int kt = 0; kt < 16; ++kt) {
        v8hf nbh[NT], nbl[NT];
        if (kt < 15) {
#pragma unroll
            for (int tt = 0; tt < NT; ++tt) {
                nbh[tt] = Bh[((size_t)nts[tt] * 16 + kt + 1) * 64 + lane];
                nbl[tt] = Bl[((size_t)nts[tt] * 16 + kt + 1) * 64 + lane];
            }
        }
        v8hf ah = *(const v8hf*)(aLds + kt * 2048 + lane * 16);
        v8hf al = *(const v8hf*)(aLds + kt * 2048 + 1024 + lane * 16);
#pragma unroll
        for (int tt = 0; tt < NT; ++tt) {
            a1[tt] = __builtin_amdgcn_mfma_f32_16x16x32_f16(ah, bh[tt], a1[tt], 0, 0, 0);
            a2[tt] = __builtin_amdgcn_mfma_f32_16x16x32_f16(ah, bl[tt], a2[tt], 0, 0, 0);
            a2[tt] = __builtin_amdgcn_mfma_f32_16x16x32_f16(al, bh[tt], a2[tt], 0, 0, 0);
        }
        if (kt < 15) {
#pragma unroll
            for (int tt = 0; tt < NT; ++tt) { bh[tt] = nbh[tt]; bl[tt] = nbl[tt]; }
        }
    }
}

// ---------------------------------------------------------------------------
// Persistent loop. 256 blocks x 512 thr, 1 block/CU (all resident).
// Runtime placement discovery: publish XCC_ID -> counted rendezvous ->
// rank blocks by (xcd, blk) -> group = 8 consecutive ranks (32 rows each).
// Homogeneous-XCD group => fast L2-coherent path; else L3 path. Correct
// under ANY placement; fast under round-robin.
// Block role: c = rank&7 owns gate cols d in [64c,64c+64) (ntiles
// {q,q+32,q+64,q+96}, q=4c+s per wave s) -> LSTM pointwise in registers;
// + logits ntile 128+c (16 vocab cols) with partial argmax exchange.
// ---------------------------------------------------------------------------
__global__ __launch_bounds__(512, 2) void k_loop(
        const float* __restrict__ proj_b, float* __restrict__ ws,
        float* __restrict__ out, const int* __restrict__ sos_p)
{
    const int blk = blockIdx.x;
    const int tid = threadIdx.x;
    const int w = tid >> 6, lane = tid & 63;
    const int s = w >> 1, m = w & 1;     // wave pair (same s) shares B stream
    const int l15 = lane & 15, l4 = lane >> 4;

    __shared__ __align__(16) unsigned char smem[65536];

    int xcd_my;
    asm volatile("s_getreg_b32 %0, hwreg(HW_REG_XCC_ID)" : "=s"(xcd_my));

    // ---- placement rendezvous ------------------------------------------
    if (tid == 0) {
        __hip_atomic_store(&g_xcd[blk], xcd_my, RLX, AGENT);
        asm volatile("s_waitcnt vmcnt(0)" ::: "memory");
        __hip_atomic_fetch_add(&g_cnt, 1u, RLX, AGENT);
        unsigned int spins = 0;
        while (__hip_atomic_load(&g_cnt, RLX, AGENT) < 256u) {
            __builtin_amdgcn_s_sleep(2);
            if (++spins > (1u << 22)) break;
        }
    }
    __syncthreads();
    int* xl = (int*)(smem);              // [0,1024)  xcd map
    int* rk = (int*)(smem + 1024);       // [1024,2048) ranks
    int* bc = (int*)(smem + 2048);       // broadcast g,c,fast
    if (tid < 256) xl[tid] = __hip_atomic_load(&g_xcd[tid], RLX, AGENT);
    __syncthreads();
    if (tid < 256) {
        int mx = xl[tid], r = 0;
        for (int i = 0; i < 256; ++i) {
            int xi = xl[i];
            if (xi < mx || (xi == mx && i < tid)) ++r;
        }
        rk[tid] = r;
    }
    __syncthreads();
    if (tid == 0) {
        int* order = (int*)(smem + 4096);
        for (int i = 0; i < 256; ++i) order[rk[i]] = i;
        int myr = rk[blk];
        int g0 = myr >> 3;
        int mn = xl[0], mxv = xl[0];
        for (int i = 0; i < 256; ++i) { mn = min(mn, xl[i]); mxv = max(mxv, xl[i]); }
        int fast = (mn != mxv);          // degenerate map -> force slow
        int x0 = xl[order[g0 * 8]];
        for (int k = 1; k < 8; ++k) if (xl[order[g0 * 8 + k]] != x0) fast = 0;
        bc[0] = g0; bc[1] = myr & 7; bc[2] = fast;
    }
    __syncthreads();
    const int g = bc[0];
    const int c = bc[1];
    const bool slow = (bc[2] == 0);
    __syncthreads();

    unsigned int* bar = &g_bar[g * 32];
    const v8hf* Bh = (const v8hf*)(ws + OFF_BHI);
    const v8hf* Bl = (const v8hf*)(ws + OFF_BLO);
    u64* part = (u64*)(ws + OFF_PART);
    const char* AhiB = (const char*)(ws + OFF_AHI) + (size_t)g * 32768;
    const char* AloB = (const char*)(ws + OFF_ALO) + (size_t)g * 32768;
    const unsigned char* aLds = smem + m * 32768;

    const int q = c * 4 + s;
    const int d = q * 16 + l15;          // this lane's gate column
    const int ntsG[4] = {q, q + 32, q + 64, q + 96};
    const int ntsL[1] = {128 + c};
    const int vcol = 16 * c + l15;       // logits column (s==0 waves)

    // persistent per-lane state
    float creg[4], ctxreg[4], cpv[4];
    float pb = proj_b[vcol];
#pragma unroll
    for (int r = 0; r < 4; ++r) {
        int rowg = g * 32 + m * 16 + l4 * 4 + r;
        creg[r] = 0.0f;
        ctxreg[r] = ws[OFF_CTX + (size_t)rowg * DDIM + d];
        cpv[r] = ws[OFF_CP + (size_t)rowg * VDIM + vcol];
    }
    const int sosv = sos_p[0];

    u64* partScr = (u64*)(smem + 16384); // [256] u64, pointwise phase only
    int* idsl    = (int*)(smem + 20480); // [32] ids

    unsigned int tgt = 0;

    for (int tau = 0; tau <= 201; ++tau) {
        // ---- stage A (group-shared): 64 KB -> LDS, batched loads --------
        {
            v4f vh[4], vl[4];
            int idx[4];
#pragma unroll
            for (int z = 0; z < 4; ++z) idx[z] = tid + 512 * z;
            if (slow) {
#pragma unroll
                for (int z = 0; z < 4; ++z) {
                    asm volatile("global_load_dwordx4 %0, %1, off sc0 sc1"
                                 : "=v"(vh[z]) : "v"(AhiB + (size_t)idx[z] * 16) : "memory");
                    asm volatile("global_load_dwordx4 %0, %1, off sc0 sc1"
                                 : "=v"(vl[z]) : "v"(AloB + (size_t)idx[z] * 16) : "memory");
                }
            } else {
#pragma unroll
                for (int z = 0; z < 4; ++z) {
                    asm volatile("global_load_dwordx4 %0, %1, off sc0"
                                 : "=v"(vh[z]) : "v"(AhiB + (size_t)idx[z] * 16) : "memory");
                    asm volatile("global_load_dwordx4 %0, %1, off sc0"
                                 : "=v"(vl[z]) : "v"(AloB + (size_t)idx[z] * 16) : "memory");
                }
            }
            asm volatile("s_waitcnt vmcnt(0)" ::: "memory");
            __builtin_amdgcn_sched_barrier(0);
#pragma unroll
            for (int z = 0; z < 4; ++z) {
                int mi = idx[z] >> 10, rem = idx[z] & 1023;
                int kt = rem >> 6, ln = rem & 63;
                *(v4f*)(smem + mi * 32768 + kt * 2048 + ln * 16) = vh[z];
                *(v4f*)(smem + mi * 32768 + kt * 2048 + 1024 + ln * 16) = vl[z];
            }
            __syncthreads();
        }

        if (tau == 201) {                // final: logits(t=200) only
            if (s == 0) {
                v4f a1[1] = {(v4f){0.f,0.f,0.f,0.f}}, a2[1] = {(v4f){0.f,0.f,0.f,0.f}};
                gemmN<1>(aLds, lane, Bh, Bl, ntsL, a1, a2);
#pragma unroll
                for (int r = 0; r < 4; ++r) {
                    float lg = (a1[0][r] + a2[0][r] * INV_LOSCALE - cpv[r]) + pb;
                    int rowg = g * 32 + m * 16 + l4 * 4 + r;
                    out[((size_t)rowg * VDIM + vcol) * TDIM + 200] = lg;
                }
            }
            break;
        }

        // ---- gates GEMM (every wave) ------------------------------------
        v4f a1g[4], a2g[4];
#pragma unroll
        for (int tt = 0; tt < 4; ++tt) {
            a1g[tt] = (v4f){0.f, 0.f, 0.f, 0.f};
            a2g[tt] = (v4f){0.f, 0.f, 0.f, 0.f};
        }
        gemmN<4>(aLds, lane, Bh, Bl, ntsG, a1g, a2g);

        // ---- logits + partial argmax (s==0 waves, tau>=1) ---------------
        if (s == 0 && tau >= 1) {
            v4f a1[1] = {(v4f){0.f,0.f,0.f,0.f}}, a2[1] = {(v4f){0.f,0.f,0.f,0.f}};
            gemmN<1>(aLds, lane, Bh, Bl, ntsL, a1, a2);
            float lgv[4];
#pragma unroll
            for (int r = 0; r < 4; ++r) {
                float lg = (a1[0][r] + a2[0][r] * INV_LOSCALE - cpv[r]) + pb;
                lgv[r] = lg;
                int rowg = g * 32 + m * 16 + l4 * 4 + r;
                out[((size_t)rowg * VDIM + vcol) * TDIM + (tau - 1)] = lg;
            }
#pragma unroll
            for (int r = 0; r < 4; ++r) {
                float bv = lgv[r];
                int   bi = vcol;
#pragma unroll
                for (int off = 1; off <= 8; off <<= 1) {
                    float ov = __shfl_xor(bv, off, 64);
                    int   oi = __shfl_xor(bi, off, 64);
                    if (ov > bv || (ov == bv && oi < bi)) { bv = ov; bi = oi; }
                }
                if (l15 == 0) {
                    int rowg = g * 32 + m * 16 + l4 * 4 + r;
                    u64 pk = ((u64)__float_as_uint(bv) << 32) | (unsigned int)bi;
                    st8_co(&part[(size_t)rowg * 8 + c], pk, slow);
                }
            }
        }

        tgt += 8; group_barrier(bar, tgt);       // logits/partials published

        // ---- combine argmax (each block locally) ------------------------
        if (tau >= 1) {
            if (tid < 256) {
                int rl = tid >> 3, cc = tid & 7;
                partScr[tid] = ld8_co(&part[(size_t)(g * 32 + rl) * 8 + cc], slow);
            }
        }
        __syncthreads();
        if (tau >= 1 && tid < 32) {
            float bv = -1e38f; int bi = 0;
#pragma unroll
            for (int cc = 0; cc < 8; ++cc) {
                u64 u = partScr[tid * 8 + cc];
                float v = __uint_as_float((unsigned int)(u >> 32));
                int   i = (int)(u & 0xffffffffu);
                if (cc == 0 || v > bv) { bv = v; bi = i; }
            }
            idsl[tid] = bi;
        }
        __syncthreads();

        // ---- pointwise LSTM in registers --------------------------------
        {
            const int ktl = (d >> 5) & 1;
            const int sel = (d >> 3) & 3;
            const int elem = d & 7;
#pragma unroll
            for (int r = 0; r < 4; ++r) {
                int rl = m * 16 + l4 * 4 + r;
                int id = (tau == 0) ? sosv : idsl[rl];
                const float* er = ws + OFF_E + (size_t)id * FD;
                float gi = a1g[0][r] + a2g[0][r] * INV_LOSCALE + er[d];
                float gf = a1g[1][r] + a2g[1][r] * INV_LOSCALE + er[d + 512];
                float gg = a1g[2][r] + a2g[2][r] * INV_LOSCALE + er[d + 1024];
                float go = a1g[3][r] + a2g[3][r] * INV_LOSCALE + er[d + 1536];
                float si = 1.0f / (1.0f + expf(-gi));
                float sf = 1.0f / (1.0f + expf(-gf));
                float so = 1.0f / (1.0f + expf(-go));
                float cn = sf * creg[r] + si * tanhf(gg);
                creg[r] = cn;
                float hn = so * tanhf(cn);
                float av = hn + ctxreg[r];
                _Float16 hh = (_Float16)av;
                _Float16 hl = (_Float16)((av - (float)hh) * LOSCALE);
                int la = (l4 * 4 + r) | (sel << 4);
                size_t so2 = (size_t)(((m * 2 + ktl) * 2 + 0) * 64 + la) * 16 + elem * 2;
                *(unsigned short*)(smem + so2)        = *(unsigned short*)&hh;
                *(unsigned short*)(smem + so2 + 1024) = *(unsigned short*)&hl;
            }
        }
        __syncthreads();
        // cooperative A-slice store: 8 KB (2 mtiles x 2 kt x hi/lo)
        {
            int m2 = tid >> 8, ktl2 = (tid >> 7) & 1, hl2 = (tid >> 6) & 1, ln2 = tid & 63;
            v4f v = *(const v4f*)(smem + (size_t)(((m2 * 2 + ktl2) * 2 + hl2) * 64 + ln2) * 16);
            char* dst = (char*)(ws + (hl2 ? OFF_ALO : OFF_AHI))
                      + ((size_t)((g * 2 + m2) * 16 + (c * 2 + ktl2)) * 64 + ln2) * 16;
            st16_co(dst, v, slow);
        }

        tgt += 8; group_barrier(bar, tgt);       // A_{tau+1} published
    }
}

extern "C" void kernel_launch(void* const* d_in, const int* in_sizes, int n_in,
                              void* d_out, int out_size, void* d_ws, size_t ws_size,
                              hipStream_t stream)
{
    const float* fm     = (const float*)d_in[0];
    const float* pooled = (const float*)d_in[1];
    const float* gamma  = (const float*)d_in[2];
    const float* beta   = (const float*)d_in[3];
    const float* W_ih   = (const float*)d_in[4];
    const float* W_hh   = (const float*)d_in[5];
    const float* b_ih   = (const float*)d_in[6];
    const float* b_hh   = (const float*)d_in[7];
    const float* embed  = (const float*)d_in[8];
    const float* attn_w = (const float*)d_in[9];
    // d_in[10] = attn_b : provably unused (softmax shift invariance)
    const float* proj_w = (const float*)d_in[11];
    const float* proj_b = (const float*)d_in[12];
    const int*   sos_p  = (const int*)d_in[13];

    float* ws  = (float*)d_ws;
    float* out = (float*)d_out;

    k_init<<<BDIM, 256, 0, stream>>>(fm, pooled, gamma, beta, attn_w, ws);
    k_E<<<FD, 256, 0, stream>>>(embed, W_ih, b_ih, b_hh, ws);
    k_cp<<<BDIM, 128, 0, stream>>>(proj_w, ws);
    k_bsetup<<<FD + VDIM, 256, 0, stream>>>(W_hh, proj_w, ws);

    // Entire 201-step recurrence in ONE persistent kernel.
    // 256 blocks (1/CU, all resident) x 512 thr; groups formed from the
    // OBSERVED XCD placement -> h-broadcast stays inside each XCD's L2.
    k_loop<<<dim3(256), 512, 0, stream>>>(proj_b, ws, out, sos_p);
}

// Round 5
// 10206.805 us; speedup vs baseline: 2.5500x; 1.1548x over previous
//
#include <hip/hip_runtime.h>
#include <math.h>

#define BDIM 1024
#define DDIM 512
#define VDIM 128
#define TDIM 201
#define FD   2048            // 4*D
#define LN_EPS 1e-5f
#define LOSCALE 4096.0f
#define INV_LOSCALE (1.0f/4096.0f)

// ws layout in floats
#define OFF_CTX 524288       // B*D    context (constant)            [read-only in loop]
#define OFF_E   1048576      // V*FD   E = embed@W_ih^T + b_ih+b_hh  [read-only in loop]
#define OFF_CP  1310720      // B*V    ctx @ proj^T                  [read-only in loop]
#define OFF_PART 1441792     // 1024*8 u64 partial argmax            [L3-coherent]
#define OFF_ABL 1572864      // 2 MB: A halves, LOCAL copies (plain store / sc0 read)
#define OFF_ABR 2097152      // 2 MB: A halves, L3 copies (sc0sc1 both sides)
#define OFF_BHI 4194304      // B hi frags                           [read-only in loop]
#define OFF_BLO 4751360      // B lo frags                           [read-only in loop]
// A half-buffer layout (per group g, half h in {0,1}):
//   byte base = (g*64 + h*32)*1024 ; hi 16 KB then lo 16 KB
//   within: ((mt*8 + ktl)*64 + lane)*16 + elem*2   (kt = h*8 + ktl)

typedef _Float16 v8hf __attribute__((ext_vector_type(8)));
typedef float    v4f  __attribute__((ext_vector_type(4)));
typedef unsigned long long u64;

#define AGENT __HIP_MEMORY_SCOPE_AGENT
#define RLX   __ATOMIC_RELAXED

// 32 group barriers (128 B apart) + rendezvous counter + placement map.
// Reset by k_init (stream-ordered before k_loop) -> replay-safe.
__device__ unsigned int g_bar[32 * 32];
__device__ unsigned int g_cnt;
__device__ int g_xcd[256];

// L3-coherent helpers (sc0 sc1: bypass L1+L2, coherent point = L3). No cache
// fences anywhere -> read-only L2 sets (B, E, CP, ctx) stay warm all steps.
__device__ __forceinline__ u64 ld8_l3(const void* p) {
    u64 r;
    asm volatile("global_load_dwordx2 %0, %1, off sc0 sc1" : "=v"(r) : "v"(p) : "memory");
    asm volatile("s_waitcnt vmcnt(0)" ::: "memory");
    __builtin_amdgcn_sched_barrier(0);
    return r;
}
__device__ __forceinline__ void st8_l3(void* p, u64 v) {
    asm volatile("global_store_dwordx2 %0, %1, off sc0 sc1" :: "v"(p), "v"(v) : "memory");
}
__device__ __forceinline__ void st16_l3(void* p, v4f v) {
    asm volatile("global_store_dwordx4 %0, %1, off sc0 sc1" :: "v"(p), "v"(v) : "memory");
}

// Group barrier (8 blocks, possibly spanning 2 XCDs). The explicit vmcnt
// drain covers inline-asm stores; atomics are agent-scope (L3). Bounded
// spin: logic bugs fail fast (wrong results), never a harness hang.
__device__ __forceinline__ void group_barrier(unsigned int* bar, unsigned int target)
{
    asm volatile("s_waitcnt vmcnt(0)" ::: "memory");
    __syncthreads();
    if (threadIdx.x == 0) {
        __hip_atomic_fetch_add(bar, 1u, RLX, AGENT);
        unsigned int spins = 0;
        while (__hip_atomic_load(bar, RLX, AGENT) < target) {
            __builtin_amdgcn_s_sleep(1);
            if (++spins > (1u << 20)) break;
        }
    }
    __syncthreads();
    asm volatile("" ::: "memory");
    __builtin_amdgcn_sched_barrier(0);
}

// B fragment layout (16x16x32 f16 MFMA), fragment-major over full K:
//   lane l holds W[n=nt*16+(l&15)][k=kt*32+(l>>4)*8+j]
__device__ __forceinline__ void split_write(float x, _Float16* hiArr, _Float16* loArr,
                                            int row, int k)
{
    _Float16 hi = (_Float16)x;
    _Float16 lo = (_Float16)((x - (float)hi) * LOSCALE);
    int lane = (row & 15) | (((k >> 3) & 3) << 4);
    size_t idx = ((size_t)((row >> 4) * 16 + (k >> 5)) * 64 + lane) * 8 + (k & 7);
    hiArr[idx] = hi;
    loArr[idx] = lo;
}

// Seed A (hi+lo) into BOTH half-buffer copies (plain stores; the implicit
// end-of-kernel agent release makes them visible to k_loop on any XCD).
__device__ __forceinline__ void seed_write(float* ws, int row, int k, float x)
{
    _Float16 hi = (_Float16)x;
    _Float16 lo = (_Float16)((x - (float)hi) * LOSCALE);
    int g = row >> 5, mt = (row >> 4) & 1;
    int lane = (row & 15) | (((k >> 3) & 3) << 4);
    int kt = k >> 5, h = kt >> 3, ktl = kt & 7, elem = k & 7;
    size_t off = ((size_t)g * 64 + (size_t)h * 32) * 1024
               + ((size_t)(mt * 8 + ktl) * 64 + lane) * 16 + (size_t)elem * 2;
    char* L = (char*)(ws + OFF_ABL);
    char* R = (char*)(ws + OFF_ABR);
    *(_Float16*)(L + off) = hi;  *(_Float16*)(L + off + 16384) = lo;
    *(_Float16*)(R + off) = hi;  *(_Float16*)(R + off + 16384) = lo;
}

// ---------------------------------------------------------------------------
// init: LayerNorm(pooled)->h0 ; softmax(fm@wf)->context ; seed A0 ; reset bars
// ---------------------------------------------------------------------------
__global__ void k_init(const float* __restrict__ fm, const float* __restrict__ pooled,
                       const float* __restrict__ gamma, const float* __restrict__ beta,
                       const float* __restrict__ attn_w, float* __restrict__ ws)
{
    int b = blockIdx.x;
    int t = threadIdx.x;                 // 256 threads
    __shared__ float red[256];
    __shared__ float s_sc[49];
    __shared__ float s_aw[49];
    __shared__ float s_ctx[DDIM];

    if (b == 0) {
        if (t < 32) g_bar[t * 32] = 0u;
        if (t == 32) g_cnt = 0u;
    }

    const float* prow = pooled + (size_t)b * DDIM;
    float x0 = prow[t], x1 = prow[t + 256];
    red[t] = x0 + x1;
    __syncthreads();
    for (int s = 128; s > 0; s >>= 1) { if (t < s) red[t] += red[t + s]; __syncthreads(); }
    float mu = red[0] * (1.0f / DDIM);
    __syncthreads();
    float d0 = x0 - mu, d1 = x1 - mu;
    red[t] = d0 * d0 + d1 * d1;
    __syncthreads();
    for (int s = 128; s > 0; s >>= 1) { if (t < s) red[t] += red[t + s]; __syncthreads(); }
    float rstd = rsqrtf(red[0] * (1.0f / DDIM) + LN_EPS);

    float h0 = d0 * rstd * gamma[t]       + beta[t];
    float h1 = d1 * rstd * gamma[t + 256] + beta[t + 256];

    if (t < 49) {
        const float* base = fm + (size_t)b * DDIM * 49 + t;
        float acc = 0.0f;
        for (int d = 0; d < DDIM; ++d) acc += base[(size_t)d * 49] * attn_w[d];
        s_sc[t] = acc;
    }
    __syncthreads();
    if (t == 0) {
        float mx = s_sc[0];
        for (int k = 1; k < 49; ++k) mx = fmaxf(mx, s_sc[k]);
        float sum = 0.0f;
        for (int k = 0; k < 49; ++k) { float e = expf(s_sc[k] - mx); s_aw[k] = e; sum += e; }
        float inv = 1.0f / sum;
        for (int k = 0; k < 49; ++k) s_aw[k] *= inv;
    }
    __syncthreads();

    float* ctx = ws + OFF_CTX + (size_t)b * DDIM;
    for (int d = t; d < DDIM; d += 256) {
        const float* base = fm + ((size_t)b * DDIM + d) * 49;
        float acc = 0.0f;
        for (int k = 0; k < 49; ++k) acc += s_aw[k] * base[k];
        ctx[d] = acc;
        s_ctx[d] = acc;
    }
    __syncthreads();

    seed_write(ws, b, t,       h0 + s_ctx[t]);
    seed_write(ws, b, t + 256, h1 + s_ctx[t + 256]);
}

// ---------------------------------------------------------------------------
// E[v,n] = embed[v,:] . W_ih[n,:] + b_ih[n] + b_hh[n]   (128 x 2048)
// ---------------------------------------------------------------------------
__global__ void k_E(const float* __restrict__ embed, const float* __restrict__ W_ih,
                    const float* __restrict__ b_ih, const float* __restrict__ b_hh,
                    float* __restrict__ ws)
{
    int n = blockIdx.x;
    int t = threadIdx.x;
    __shared__ float wrow[DDIM];
    wrow[t]       = W_ih[(size_t)n * DDIM + t];
    wrow[t + 256] = W_ih[(size_t)n * DDIM + t + 256];
    __syncthreads();
    if (t < VDIM) {
        const float* er = embed + (size_t)t * DDIM;
        float acc = 0.0f;
        for (int d = 0; d < DDIM; ++d) acc += er[d] * wrow[d];
        ws[OFF_E + (size_t)t * FD + n] = acc + b_ih[n] + b_hh[n];
    }
}

__global__ void k_cp(const float* __restrict__ proj_w, float* __restrict__ ws)
{
    int b = blockIdx.x;
    int t = threadIdx.x;                 // 128
    __shared__ float crow[DDIM];
    const float* ctx = ws + OFF_CTX + (size_t)b * DDIM;
    for (int d = t; d < DDIM; d += 128) crow[d] = ctx[d];
    __syncthreads();
    const float* pr = proj_w + (size_t)t * DDIM;
    float acc = 0.0f;
    for (int d = 0; d < DDIM; ++d) acc += crow[d] * pr[d];
    ws[OFF_CP + (size_t)b * VDIM + t] = acc;
}

__global__ void k_bsetup(const float* __restrict__ W_hh, const float* __restrict__ proj_w,
                         float* __restrict__ ws)
{
    int n = blockIdx.x;                  // 0..2175
    int t = threadIdx.x;                 // 256
    const float* src = (n < FD) ? (W_hh + (size_t)n * DDIM)
                                : (proj_w + (size_t)(n - FD) * DDIM);
    _Float16* Bhi = (_Float16*)(ws + OFF_BHI);
    _Float16* Blo = (_Float16*)(ws + OFF_BLO);
    for (int k = t; k < DDIM; k += 256)
        split_write(src[k], Bhi, Blo, n, k);
}

// 8-kt GEMM sweep starting at kt=k0: A from LDS, B from L2-resident global,
// depth-1 B prefetch; accumulators carry across calls.
template<int NT>
__device__ __forceinline__ void gemmK8(const unsigned char* aLds, int lane,
                                       const v8hf* __restrict__ Bh,
                                       const v8hf* __restrict__ Bl,
                                       const int* nts, int k0, v4f* a1, v4f* a2)
{
    v8hf bh[NT], bl[NT];
#pragma unroll
    for (int tt = 0; tt < NT; ++tt) {
        bh[tt] = Bh[((size_t)nts[tt] * 16 + k0) * 64 + lane];
        bl[tt] = Bl[((size_t)nts[tt] * 16 + k0) * 64 + lane];
    }
#pragma unroll
    for (int i = 0; i < 8; ++i) {
        int kt = k0 + i;
        v8hf nbh[NT], nbl[NT];
        if (i < 7) {
#pragma unroll
            for (int tt = 0; tt < NT; ++tt) {
                nbh[tt] = Bh[((size_t)nts[tt] * 16 + kt + 1) * 64 + lane];
                nbl[tt] = Bl[((size_t)nts[tt] * 16 + kt + 1) * 64 + lane];
            }
        }
        v8hf ah = *(const v8hf*)(aLds + kt * 2048 + lane * 16);
        v8hf al = *(const v8hf*)(aLds + kt * 2048 + 1024 + lane * 16);
#pragma unroll
        for (int tt = 0; tt < NT; ++tt) {
            a1[tt] = __builtin_amdgcn_mfma_f32_16x16x32_f16(ah, bh[tt], a1[tt], 0, 0, 0);
            a2[tt] = __builtin_amdgcn_mfma_f32_16x16x32_f16(ah, bl[tt], a2[tt], 0, 0, 0);
            a2[tt] = __builtin_amdgcn_mfma_f32_16x16x32_f16(al, bh[tt], a2[tt], 0, 0, 0);
        }
        if (i < 7) {
#pragma unroll
            for (int tt = 0; tt < NT; ++tt) { bh[tt] = nbh[tt]; bl[tt] = nbl[tt]; }
        }
    }
}

// ---------------------------------------------------------------------------
// Persistent loop, 256 blocks x 512 thr (1/CU). Runtime placement map ->
// rank by (xcd, blk) -> XCD pair p = ranks [64p,64p+64). Group g = p*8+j has
// c0..3 on the pair's first XCD, c4..7 on the second => per-XCD B = HALF
// (2.23 MB, L2-resident; the round-4 thrash is gone). h/A halves split by
// kt: half0 = kt0..7 (made by c0..3), half1 = kt8..15. Producers dual-write
// (plain->ABL for same-XCD readers, sc0sc1->ABR for cross-XCD). Consumers
// pick per-half: fast -> sc0 from ABL, else sc0sc1 from ABR. Local half is
// staged+computed first while remote loads are in flight (vmcnt-split).
// ---------------------------------------------------------------------------
__global__ __launch_bounds__(512, 2) void k_loop(
        const float* __restrict__ proj_b, float* __restrict__ ws,
        float* __restrict__ out, const int* __restrict__ sos_p)
{
    const int blk = blockIdx.x;
    const int tid = threadIdx.x;
    const int w = tid >> 6, lane = tid & 63;
    const int s = w >> 1, m = w & 1;     // 4 s-slices x 2 mtiles
    const int l15 = lane & 15, l4 = lane >> 4;

    __shared__ __align__(16) unsigned char smem[65536];

    int xcd_my;
    asm volatile("s_getreg_b32 %0, hwreg(HW_REG_XCC_ID)" : "=s"(xcd_my));

    // ---- placement rendezvous ------------------------------------------
    if (tid == 0) {
        __hip_atomic_store(&g_xcd[blk], xcd_my, RLX, AGENT);
        asm volatile("s_waitcnt vmcnt(0)" ::: "memory");
        __hip_atomic_fetch_add(&g_cnt, 1u, RLX, AGENT);
        unsigned int spins = 0;
        while (__hip_atomic_load(&g_cnt, RLX, AGENT) < 256u) {
            __builtin_amdgcn_s_sleep(2);
            if (++spins > (1u << 22)) break;
        }
    }
    __syncthreads();
    int* xl = (int*)(smem);              // [0,1024)
    int* rk = (int*)(smem + 1024);       // [1024,2048)
    int* bc = (int*)(smem + 2048);       // broadcast {g, c, fast0, fast1}
    if (tid < 256) xl[tid] = __hip_atomic_load(&g_xcd[tid], RLX, AGENT);
    __syncthreads();
    if (tid < 256) {
        int mx = xl[tid], r = 0;
        for (int i = 0; i < 256; ++i) {
            int xi = xl[i];
            if (xi < mx || (xi == mx && i < tid)) ++r;
        }
        rk[tid] = r;
    }
    __syncthreads();
    if (tid == 0) {
        int* order = (int*)(smem + 4096);
        for (int i = 0; i < 256; ++i) order[rk[i]] = i;
        int myr = rk[blk];
        int p = myr >> 6, lr = myr & 63;
        int j, c;
        if (lr < 32) { j = lr >> 2; c = lr & 3; }
        else         { j = (lr - 32) >> 2; c = 4 + ((lr - 32) & 3); }
        int base0 = p * 64 + j * 4;          // half0 producers (c=0..3)
        int base1 = p * 64 + 32 + j * 4;     // half1 producers (c=4..7)
        int x0 = xl[order[base0]], hom0 = 1;
        for (int k = 1; k < 4; ++k) if (xl[order[base0 + k]] != x0) hom0 = 0;
        int x1 = xl[order[base1]], hom1 = 1;
        for (int k = 1; k < 4; ++k) if (xl[order[base1 + k]] != x1) hom1 = 0;
        int mn = xl[0], mxv = xl[0];
        for (int i = 0; i < 256; ++i) { mn = min(mn, xl[i]); mxv = max(mxv, xl[i]); }
        int sane = (mn != mxv);              // garbage XCC_ID map -> force L3
        bc[0] = p * 8 + j;
        bc[1] = c;
        bc[2] = sane && hom0 && (x0 == xl[blk]);
        bc[3] = sane && hom1 && (x1 == xl[blk]);
    }
    __syncthreads();
    const int g = bc[0];
    const int c = bc[1];
    const bool fast0 = (bc[2] != 0);
    const bool fast1 = (bc[3] != 0);
    __syncthreads();

    unsigned int* bar = &g_bar[g * 32];
    const v8hf* Bh = (const v8hf*)(ws + OFF_BHI);
    const v8hf* Bl = (const v8hf*)(ws + OFF_BLO);
    u64* part = (u64*)(ws + OFF_PART);
    char* ABL = (char*)(ws + OFF_ABL);
    char* ABR = (char*)(ws + OFF_ABR);
    const unsigned char* aLds = smem + m * 32768;

    const char* baseH[2];
    bool fH[2] = {fast0, fast1};
    baseH[0] = (fast0 ? ABL : ABR) + ((size_t)g * 64 +  0) * 1024;
    baseH[1] = (fast1 ? ABL : ABR) + ((size_t)g * 64 + 32) * 1024;
    const int lh = fast0 ? 0 : (fast1 ? 1 : (c >> 2));   // stage/compute first
    const int rh = 1 - lh;
    const int hb = c >> 2;                                // half I produce

    const int q = c * 4 + s;
    const int d = q * 16 + l15;          // this lane's gate column
    const int ntsG[4] = {q, q + 32, q + 64, q + 96};
    const int ntsL[1] = {128 + c};
    const int vcol = 16 * c + l15;       // logits column (s==0 waves)

    // persistent per-lane state
    float creg[4], ctxreg[4], cpv[4];
    float pb = proj_b[vcol];
#pragma unroll
    for (int r = 0; r < 4; ++r) {
        int rowg = g * 32 + m * 16 + l4 * 4 + r;
        creg[r] = 0.0f;
        ctxreg[r] = ws[OFF_CTX + (size_t)rowg * DDIM + d];
        cpv[r] = ws[OFF_CP + (size_t)rowg * VDIM + vcol];
    }
    const int sosv = sos_p[0];

    u64* partScr = (u64*)(smem + 16384); // reuse staging area post-GEMM
    int* idsl    = (int*)(smem + 20480);

    const int ktl_t = tid >> 6;          // 0..7 : my staged ktl
    const int ln_t  = tid & 63;
    const size_t soff = (size_t)ktl_t * 1024 + (size_t)ln_t * 16;

    unsigned int tgt = 0;

    for (int tau = 0; tau <= 201; ++tau) {
        const bool doGates = (tau < 201);
        const bool doLog   = (s == 0) && (tau >= 1);

        // ---- stage: local half first, remote in flight ------------------
        v4f Lh0, Ll0, Lh1, Ll1, Rh0, Rl0, Rh1, Rl1;
        {
            const char* pL0 = baseH[lh] + soff;
            const char* pL1 = baseH[lh] + 8192 + soff;
            const char* pR0 = baseH[rh] + soff;
            const char* pR1 = baseH[rh] + 8192 + soff;
            if (fH[lh]) {
                asm volatile("global_load_dwordx4 %0, %1, off sc0" : "=v"(Lh0) : "v"(pL0) : "memory");
                asm volatile("global_load_dwordx4 %0, %1, off sc0" : "=v"(Ll0) : "v"(pL0 + 16384) : "memory");
                asm volatile("global_load_dwordx4 %0, %1, off sc0" : "=v"(Lh1) : "v"(pL1) : "memory");
                asm volatile("global_load_dwordx4 %0, %1, off sc0" : "=v"(Ll1) : "v"(pL1 + 16384) : "memory");
            } else {
                asm volatile("global_load_dwordx4 %0, %1, off sc0 sc1" : "=v"(Lh0) : "v"(pL0) : "memory");
                asm volatile("global_load_dwordx4 %0, %1, off sc0 sc1" : "=v"(Ll0) : "v"(pL0 + 16384) : "memory");
                asm volatile("global_load_dwordx4 %0, %1, off sc0 sc1" : "=v"(Lh1) : "v"(pL1) : "memory");
                asm volatile("global_load_dwordx4 %0, %1, off sc0 sc1" : "=v"(Ll1) : "v"(pL1 + 16384) : "memory");
            }
            if (fH[rh]) {
                asm volatile("global_load_dwordx4 %0, %1, off sc0" : "=v"(Rh0) : "v"(pR0) : "memory");
                asm volatile("global_load_dwordx4 %0, %1, off sc0" : "=v"(Rl0) : "v"(pR0 + 16384) : "memory");
                asm volatile("global_load_dwordx4 %0, %1, off sc0" : "=v"(Rh1) : "v"(pR1) : "memory");
                asm volatile("global_load_dwordx4 %0, %1, off sc0" : "=v"(Rl1) : "v"(pR1 + 16384) : "memory");
            } else {
                asm volatile("global_load_dwordx4 %0, %1, off sc0 sc1" : "=v"(Rh0) : "v"(pR0) : "memory");
                asm volatile("global_load_dwordx4 %0, %1, off sc0 sc1" : "=v"(Rl0) : "v"(pR0 + 16384) : "memory");
                asm volatile("global_load_dwordx4 %0, %1, off sc0 sc1" : "=v"(Rh1) : "v"(pR1) : "memory");
                asm volatile("global_load_dwordx4 %0, %1, off sc0 sc1" : "=v"(Rl1) : "v"(pR1 + 16384) : "memory");
            }
        }
        asm volatile("s_waitcnt vmcnt(4)" ::: "memory");   // 4 oldest = local
        __builtin_amdgcn_sched_barrier(0);
        {
            int kt = lh * 8 + ktl_t;
            *(v4f*)(smem +         kt * 2048 +        ln_t * 16) = Lh0;
            *(v4f*)(smem +         kt * 2048 + 1024 + ln_t * 16) = Ll0;
            *(v4f*)(smem + 32768 + kt * 2048 +        ln_t * 16) = Lh1;
            *(v4f*)(smem + 32768 + kt * 2048 + 1024 + ln_t * 16) = Ll1;
        }
        __syncthreads();

        // ---- chunk 1: local-half kts (remote loads still in flight) -----
        v4f a1g[4], a2g[4], a1l[1], a2l[1];
#pragma unroll
        for (int tt = 0; tt < 4; ++tt) {
            a1g[tt] = (v4f){0.f, 0.f, 0.f, 0.f};
            a2g[tt] = (v4f){0.f, 0.f, 0.f, 0.f};
        }
        a1l[0] = (v4f){0.f, 0.f, 0.f, 0.f};
        a2l[0] = (v4f){0.f, 0.f, 0.f, 0.f};
        if (doGates) gemmK8<4>(aLds, lane, Bh, Bl, ntsG, lh * 8, a1g, a2g);
        if (doLog)   gemmK8<1>(aLds, lane, Bh, Bl, ntsL, lh * 8, a1l, a2l);

        asm volatile("s_waitcnt vmcnt(0)" ::: "memory");
        __builtin_amdgcn_sched_barrier(0);
        {
            int kt = rh * 8 + ktl_t;
            *(v4f*)(smem +         kt * 2048 +        ln_t * 16) = Rh0;
            *(v4f*)(smem +         kt * 2048 + 1024 + ln_t * 16) = Rl0;
            *(v4f*)(smem + 32768 + kt * 2048 +        ln_t * 16) = Rh1;
            *(v4f*)(smem + 32768 + kt * 2048 + 1024 + ln_t * 16) = Rl1;
        }
        __syncthreads();

        // ---- chunk 2: remote-half kts -----------------------------------
        if (doGates) gemmK8<4>(aLds, lane, Bh, Bl, ntsG, rh * 8, a1g, a2g);
        if (doLog)   gemmK8<1>(aLds, lane, Bh, Bl, ntsL, rh * 8, a1l, a2l);

        // ---- logits out + partial argmax --------------------------------
        if (doLog) {
            float lgv[4];
#pragma unroll
            for (int r = 0; r < 4; ++r) {
                float lg = (a1l[0][r] + a2l[0][r] * INV_LOSCALE - cpv[r]) + pb;
                lgv[r] = lg;
                int rowg = g * 32 + m * 16 + l4 * 4 + r;
                out[((size_t)rowg * VDIM + vcol) * TDIM + (tau - 1)] = lg;
            }
            if (tau < 201) {
#pragma unroll
                for (int r = 0; r < 4; ++r) {
                    float bv = lgv[r];
                    int   bi = vcol;
#pragma unroll
                    for (int off = 1; off <= 8; off <<= 1) {
                        float ov = __shfl_xor(bv, off, 64);
                        int   oi = __shfl_xor(bi, off, 64);
                        if (ov > bv || (ov == bv && oi < bi)) { bv = ov; bi = oi; }
                    }
                    if (l15 == 0) {
                        int rowg = g * 32 + m * 16 + l4 * 4 + r;
                        u64 pk = ((u64)__float_as_uint(bv) << 32) | (unsigned int)bi;
                        st8_l3(&part[(size_t)rowg * 8 + c], pk);
                    }
                }
            }
        }
        if (tau == 201) break;

        tgt += 8; group_barrier(bar, tgt);       // logits/partials published

        // ---- combine argmax (each block locally; ascending c, strict >) --
        if (tau >= 1) {
            if (tid < 256) {
                int rl = tid >> 3, cc = tid & 7;
                partScr[tid] = ld8_l3(&part[(size_t)(g * 32 + rl) * 8 + cc]);
            }
        }
        __syncthreads();
        if (tau >= 1 && tid < 32) {
            float bv = -1e38f; int bi = 0;
#pragma unroll
            for (int cc = 0; cc < 8; ++cc) {
                u64 u = partScr[tid * 8 + cc];
                float v = __uint_as_float((unsigned int)(u >> 32));
                int   i = (int)(u & 0xffffffffu);
                if (cc == 0 || v > bv) { bv = v; bi = i; }
            }
            idsl[tid] = bi;
        }
        __syncthreads();

        // ---- pointwise LSTM in registers --------------------------------
        {
            const int ktl = (d >> 5) & 1;
            const int sel = (d >> 3) & 3;
            const int elem = d & 7;
#pragma unroll
            for (int r = 0; r < 4; ++r) {
                int rl = m * 16 + l4 * 4 + r;
                int id = (tau == 0) ? sosv : idsl[rl];
                const float* er = ws + OFF_E + (size_t)id * FD;
                float gi = a1g[0][r] + a2g[0][r] * INV_LOSCALE + er[d];
                float gf = a1g[1][r] + a2g[1][r] * INV_LOSCALE + er[d + 512];
                float gg = a1g[2][r] + a2g[2][r] * INV_LOSCALE + er[d + 1024];
                float go = a1g[3][r] + a2g[3][r] * INV_LOSCALE + er[d + 1536];
                float si = 1.0f / (1.0f + expf(-gi));
                float sf = 1.0f / (1.0f + expf(-gf));
                float so = 1.0f / (1.0f + expf(-go));
                float cn = sf * creg[r] + si * tanhf(gg);
                creg[r] = cn;
                float hn = so * tanhf(cn);
                float av = hn + ctxreg[r];
                _Float16 hh = (_Float16)av;
                _Float16 hl = (_Float16)((av - (float)hh) * LOSCALE);
                int la = (l4 * 4 + r) | (sel << 4);
                size_t so2 = (size_t)(((m * 2 + ktl) * 2 + 0) * 64 + la) * 16 + elem * 2;
                *(unsigned short*)(smem + so2)        = *(unsigned short*)&hh;
                *(unsigned short*)(smem + so2 + 1024) = *(unsigned short*)&hl;
            }
        }
        __syncthreads();
        // cooperative A-slice store: dual-write 8 KB (L plain + R sc1)
        {
            int m2 = tid >> 8, ktl2 = (tid >> 7) & 1, hl2 = (tid >> 6) & 1, ln2 = tid & 63;
            v4f v = *(const v4f*)(smem + (size_t)(((m2 * 2 + ktl2) * 2 + hl2) * 64 + ln2) * 16);
            int klh = (c & 3) * 2 + ktl2;
            size_t off = ((size_t)g * 64 + (size_t)hb * 32) * 1024
                       + ((size_t)(m2 * 8 + klh) * 64 + ln2) * 16
                       + (hl2 ? 16384 : 0);
            *(volatile v4f*)(ABL + off) = v;
            st16_l3(ABR + off, v);
        }

        tgt += 8; group_barrier(bar, tgt);       // A_{tau+1} published
    }
}

extern "C" void kernel_launch(void* const* d_in, const int* in_sizes, int n_in,
                              void* d_out, int out_size, void* d_ws, size_t ws_size,
                              hipStream_t stream)
{
    const float* fm     = (const float*)d_in[0];
    const float* pooled = (const float*)d_in[1];
    const float* gamma  = (const float*)d_in[2];
    const float* beta   = (const float*)d_in[3];
    const float* W_ih   = (const float*)d_in[4];
    const float* W_hh   = (const float*)d_in[5];
    const float* b_ih   = (const float*)d_in[6];
    const float* b_hh   = (const float*)d_in[7];
    const float* embed  = (const float*)d_in[8];
    const float* attn_w = (const float*)d_in[9];
    // d_in[10] = attn_b : provably unused (softmax shift invariance)
    const float* proj_w = (const float*)d_in[11];
    const float* proj_b = (const float*)d_in[12];
    const int*   sos_p  = (const int*)d_in[13];

    float* ws  = (float*)d_ws;
    float* out = (float*)d_out;

    k_init<<<BDIM, 256, 0, stream>>>(fm, pooled, gamma, beta, attn_w, ws);
    k_E<<<FD, 256, 0, stream>>>(embed, W_ih, b_ih, b_hh, ws);
    k_cp<<<BDIM, 128, 0, stream>>>(proj_w, ws);
    k_bsetup<<<FD + VDIM, 256, 0, stream>>>(W_hh, proj_w, ws);

    // Entire 201-step recurrence in ONE persistent kernel.
    // 256 blocks (1/CU) x 512 thr; groups of 8 split 4+4 across an XCD PAIR
    // (observed placement) -> per-XCD B halved (L2-resident), A exchanged
    // locally via L2 + cross-XCD via a dual-written L3 copy.
    k_loop<<<dim3(256), 512, 0, stream>>>(proj_b, ws, out, sos_p);
}